// Round 3
// baseline (4167.200 us; speedup 1.0000x reference)
//
#include <hip/hip_runtime.h>
#include <hip/hip_bf16.h>

// ---------------- scatter: entity GEMM + relu + scatter-add ----------------
// emb [64,512,256] f32, xy [64,512,16] i32, w [32,256] f32 -> scat [64,32,64,64] f32 (pre-zeroed)
__global__ __launch_bounds__(256) void k_scatter(const float* __restrict__ emb,
                                                 const int* __restrict__ xy,
                                                 const float* __restrict__ w,
                                                 float* __restrict__ scat) {
  __shared__ float wl[32 * 257];  // +1 pad: lanes c=0..31 hit distinct banks
  __shared__ float el[8 * 256];
  const int tid = threadIdx.x;
  for (int i = tid; i < 32 * 256; i += 256) {
    int c = i >> 8, d = i & 255;
    wl[c * 257 + d] = w[i];
  }
  const int g0 = blockIdx.x * 8;  // 8 entities per block
  for (int i = tid; i < 2048; i += 256) el[i] = emb[(size_t)g0 * 256 + i];
  __syncthreads();
  const int e = tid >> 5, c = tid & 31;
  const int g = g0 + e;
  const float* er = &el[e << 8];
  const float* wr = &wl[c * 257];
  float acc = 0.f;
#pragma unroll 16
  for (int d = 0; d < 256; ++d) acc += er[d] * wr[d];
  const int* bp = xy + (size_t)g * 16;
  int xv = 0, yv = 0;
#pragma unroll
  for (int j = 0; j < 8; ++j) xv = (xv << 1) | bp[j];
#pragma unroll
  for (int j = 8; j < 16; ++j) yv = (yv << 1) | bp[j];
  const bool valid = (bp[0] != -1000000000);
  float v = acc > 0.f ? acc : 0.f;
  if (valid && v != 0.f) {
    xv >>= 2;
    yv >>= 2;
    const int b = g >> 9;
    atomicAdd(&scat[(((size_t)b * 32 + c) << 12) + (yv << 6) + xv], v);
  }
}

// ---------------- project: concat + 1x1 conv + relu ----------------
__global__ __launch_bounds__(256) void k_project(const float* __restrict__ scat,
                                                 const float* __restrict__ xin,
                                                 const float* __restrict__ pw,
                                                 const float* __restrict__ pb,
                                                 float* __restrict__ out) {
  const int idx = blockIdx.x * 256 + threadIdx.x;  // 8388608 total
  const int yx = idx & 4095;
  const int co = (idx >> 12) & 31;
  const int b = idx >> 17;
  float acc = pb[co];
  const float* sp = scat + ((size_t)b << 17) + yx;       // [B,32,4096]
  const float* xp = xin + (size_t)b * 73728 + yx;        // [B,18,4096]
  const float* wp = pw + co * 50;
#pragma unroll
  for (int ci = 0; ci < 32; ++ci) acc += wp[ci] * sp[ci << 12];
#pragma unroll
  for (int ci = 0; ci < 18; ++ci) acc += wp[32 + ci] * xp[ci << 12];
  out[idx] = acc > 0.f ? acc : 0.f;
}

// ---------------- 4x4 stride-2 pad-1 conv + relu (direct) ----------------
template <int CIN, int COUT, int HIN>
__global__ __launch_bounds__(256) void k_dsconv(const float* __restrict__ in,
                                                const float* __restrict__ w,
                                                const float* __restrict__ bias,
                                                float* __restrict__ out) {
  constexpr int HOUT = HIN / 2;
  const int idx = blockIdx.x * 256 + threadIdx.x;
  const int wo = idx % HOUT;
  int t = idx / HOUT;
  const int ho = t % HOUT;
  t /= HOUT;
  const int co = t % COUT;
  const int b = t / COUT;
  float acc = bias[co];
  const float* ib = in + (size_t)b * CIN * HIN * HIN;
  const float* wb = w + (size_t)co * CIN * 16;
  for (int ci = 0; ci < CIN; ++ci) {
    const float* ic = ib + ci * HIN * HIN;
    const float* wc = wb + ci * 16;
#pragma unroll
    for (int ky = 0; ky < 4; ++ky) {
      const int hi = 2 * ho - 1 + ky;
      if (hi < 0 || hi >= HIN) continue;
#pragma unroll
      for (int kx = 0; kx < 4; ++kx) {
        const int wi = 2 * wo - 1 + kx;
        if (wi < 0 || wi >= HIN) continue;
        acc += wc[ky * 4 + kx] * ic[hi * HIN + wi];
      }
    }
  }
  out[idx] = acc > 0.f ? acc : 0.f;
}

// ---------------- 3x3 pad-1 conv on 8x8, fused batch-stat accumulation ----------------
// in [64,128,8,8] f32, wf [128,128,3,3] f32 -> out pre-BN, stats {sum[128], sumsq[128]} (pre-zeroed)
// block = 4 waves; wave handles 4 consecutive co of one b; LDS: 10x10 halo per ci (no bounds branches)
__global__ __launch_bounds__(256) void k_resconv(const float* __restrict__ in,
                                                 const float* __restrict__ wf,
                                                 float* __restrict__ out,
                                                 float* __restrict__ stats) {
  __shared__ float lin[12800];  // 128 ch * 100 (10x10 halo)
  const int tid = threadIdx.x;
  const int b = blockIdx.x >> 3;              // 8 blocks per b
  const int co_base = (blockIdx.x & 7) << 4;  // 16 co per block
  for (int i = tid; i < 12800; i += 256) lin[i] = 0.f;
  __syncthreads();
  const float* ib = in + (size_t)b * 8192;
  for (int i = tid; i < 8192; i += 256) {
    const int ci = i >> 6, p = i & 63;
    lin[ci * 100 + ((p >> 3) + 1) * 10 + (p & 7) + 1] = ib[i];
  }
  __syncthreads();
  const int wq = __builtin_amdgcn_readfirstlane((int)(tid >> 6));  // force wave-uniform
  const int lane = tid & 63;
  const int co0 = co_base + wq * 4;
  const int ho = lane >> 3, wo = lane & 7;
  float a0 = 0.f, a1 = 0.f, a2 = 0.f, a3 = 0.f;
  const float* wbase = wf + (size_t)co0 * 1152;  // uniform -> scalar loads
  for (int ci = 0; ci < 128; ++ci) {
    const float* lp = &lin[ci * 100 + ho * 10 + wo];
    const float r0 = lp[0], r1 = lp[1], r2 = lp[2];
    const float r3 = lp[10], r4 = lp[11], r5 = lp[12];
    const float r6 = lp[20], r7 = lp[21], r8 = lp[22];
    const float* w0 = wbase + ci * 9;
    const float* w1 = w0 + 1152;
    const float* w2 = w0 + 2304;
    const float* w3 = w0 + 3456;
    a0 += w0[0] * r0 + w0[1] * r1 + w0[2] * r2 + w0[3] * r3 + w0[4] * r4 +
          w0[5] * r5 + w0[6] * r6 + w0[7] * r7 + w0[8] * r8;
    a1 += w1[0] * r0 + w1[1] * r1 + w1[2] * r2 + w1[3] * r3 + w1[4] * r4 +
          w1[5] * r5 + w1[6] * r6 + w1[7] * r7 + w1[8] * r8;
    a2 += w2[0] * r0 + w2[1] * r1 + w2[2] * r2 + w2[3] * r3 + w2[4] * r4 +
          w2[5] * r5 + w2[6] * r6 + w2[7] * r7 + w2[8] * r8;
    a3 += w3[0] * r0 + w3[1] * r1 + w3[2] * r2 + w3[3] * r3 + w3[4] * r4 +
          w3[5] * r5 + w3[6] * r6 + w3[7] * r7 + w3[8] * r8;
  }
  const size_t ob = ((size_t)b * 128 + co0) * 64 + lane;
  out[ob] = a0;
  out[ob + 64] = a1;
  out[ob + 128] = a2;
  out[ob + 192] = a3;
  float sv[4] = {a0, a1, a2, a3};
#pragma unroll
  for (int j = 0; j < 4; ++j) {
    float s = sv[j], q = sv[j] * sv[j];
#pragma unroll
    for (int off = 32; off > 0; off >>= 1) {
      s += __shfl_down(s, off);
      q += __shfl_down(q, off);
    }
    if (lane == 0) {
      atomicAdd(&stats[co0 + j], s);
      atomicAdd(&stats[128 + co0 + j], q);
    }
  }
}

// ---------------- BN (batch stats) + relu ----------------
__global__ __launch_bounds__(256) void k_bnrelu(const float* __restrict__ in,
                                                const float* __restrict__ stats,
                                                const float* __restrict__ g,
                                                const float* __restrict__ bb,
                                                float* __restrict__ out) {
  const int idx = blockIdx.x * 256 + threadIdx.x;  // 524288
  const int co = (idx >> 6) & 127;
  const float mu = stats[co] * (1.f / 4096.f);
  const float var = stats[128 + co] * (1.f / 4096.f) - mu * mu;
  const float v = g[co] * (in[idx] - mu) * rsqrtf(var + 1e-5f) + bb[co];
  out[idx] = v > 0.f ? v : 0.f;
}

// ---------------- BN + residual add + relu + map_skip accumulate ----------------
__global__ __launch_bounds__(256) void k_bnadd(const float* __restrict__ in,
                                               const float* __restrict__ stats,
                                               const float* __restrict__ g,
                                               const float* __restrict__ bb,
                                               const float* __restrict__ ident,
                                               float* __restrict__ hout,
                                               float* __restrict__ ms) {
  const int idx = blockIdx.x * 256 + threadIdx.x;
  const int co = (idx >> 6) & 127;
  const float mu = stats[co] * (1.f / 4096.f);
  const float var = stats[128 + co] * (1.f / 4096.f) - mu * mu;
  float v = g[co] * (in[idx] - mu) * rsqrtf(var + 1e-5f) + bb[co];
  v += ident[idx];
  v = v > 0.f ? v : 0.f;
  hout[idx] = v;
  ms[idx] += v;
}

__global__ __launch_bounds__(256) void k_copy(const float* __restrict__ a,
                                              float* __restrict__ b) {
  const int i = blockIdx.x * 256 + threadIdx.x;
  b[i] = a[i];
}

// ---------------- FC: [64,8192] x [256,8192]^T + b, relu -> f32 out ----------------
__global__ __launch_bounds__(256) void k_fc(const float* __restrict__ h,
                                            const float* __restrict__ w,
                                            const float* __restrict__ bias,
                                            float* __restrict__ out) {
  const int wid = blockIdx.x * 4 + (threadIdx.x >> 6);
  const int lane = threadIdx.x & 63;
  const int b = wid >> 8, j = wid & 255;
  const float* hp = h + ((size_t)b << 13);
  const float* wp = w + ((size_t)j << 13);
  float acc = 0.f;
  for (int k = lane; k < 8192; k += 64) acc += hp[k] * wp[k];
#pragma unroll
  for (int off = 32; off > 0; off >>= 1) acc += __shfl_down(acc, off);
  if (lane == 0) {
    float v = acc + bias[j];
    out[b * 256 + j] = v > 0.f ? v : 0.f;
  }
}

extern "C" void kernel_launch(void* const* d_in, const int* in_sizes, int n_in,
                              void* d_out, int out_size, void* d_ws, size_t ws_size,
                              hipStream_t stream) {
  const float* xin = (const float*)d_in[0];
  const float* emb = (const float*)d_in[1];
  const int* xy = (const int*)d_in[2];
  const float* c1w = (const float*)d_in[3];
  const float* pw = (const float*)d_in[4];
  const float* pb = (const float*)d_in[5];
  const float* d1w = (const float*)d_in[6];
  const float* d1b = (const float*)d_in[7];
  const float* d2w = (const float*)d_in[8];
  const float* d2b = (const float*)d_in[9];
  const float* d3w = (const float*)d_in[10];
  const float* d3b = (const float*)d_in[11];
  const float* rc1w = (const float*)d_in[12];
  const float* rbn1g = (const float*)d_in[13];
  const float* rbn1b = (const float*)d_in[14];
  const float* rc2w = (const float*)d_in[15];
  const float* rbn2g = (const float*)d_in[16];
  const float* rbn2b = (const float*)d_in[17];
  const float* fcw = (const float*)d_in[18];
  const float* fcb = (const float*)d_in[19];

  float* out0 = (float*)d_out;          // map_skip [64,128,8,8] f32 (reference output dtype)
  float* out1 = out0 + 524288;          // embedded_spatial [64,256] f32

  float* F = (float*)d_ws;              // ~72 MB used; round-2 ran with no fault at this extent
  float* scat = F + 0;                  // 8388608  [B,32,64,64]
  float* h0 = F + 8388608;              // 8388608  [B,32,64,64]   (dead after ds1)
  float* h1 = F + 0;                    // 4194304  [B,64,32,32]   (reuses scat)
  float* h2 = F + 4194304;              // 2097152  [B,128,16,16]
  float* hA = F + 6291456;              // 524288   h ping
  float* hB = F + 6815744;              // 524288   h pong
  float* tmp = F + 7340032;             // 524288   conv pre-BN
  float* obuf = F + 7864320;            // 524288   post-BN1
  float* stats = F + 17956864;          // 2048     8 x {sum[128],sumsq[128]}

  hipMemsetAsync(scat, 0, 8388608 * sizeof(float), stream);
  hipMemsetAsync(stats, 0, 2048 * sizeof(float), stream);

  k_scatter<<<4096, 256, 0, stream>>>(emb, xy, c1w, scat);
  k_project<<<32768, 256, 0, stream>>>(scat, xin, pw, pb, h0);
  k_dsconv<32, 64, 64><<<16384, 256, 0, stream>>>(h0, d1w, d1b, h1);
  k_dsconv<64, 128, 32><<<8192, 256, 0, stream>>>(h1, d2w, d2b, h2);
  k_dsconv<128, 128, 16><<<2048, 256, 0, stream>>>(h2, d3w, d3b, hA);
  k_copy<<<2048, 256, 0, stream>>>(hA, out0);  // map_skip accumulator lives in d_out (f32)

  float* cur = hA;
  float* nxt = hB;
  for (int i = 0; i < 4; ++i) {
    float* sA = stats + i * 512;
    float* sB = stats + i * 512 + 256;
    k_resconv<<<512, 256, 0, stream>>>(cur, rc1w + (size_t)i * 147456, tmp, sA);
    k_bnrelu<<<2048, 256, 0, stream>>>(tmp, sA, rbn1g + i * 128, rbn1b + i * 128, obuf);
    k_resconv<<<512, 256, 0, stream>>>(obuf, rc2w + (size_t)i * 147456, tmp, sB);
    k_bnadd<<<2048, 256, 0, stream>>>(tmp, sB, rbn2g + i * 128, rbn2b + i * 128, cur, nxt, out0);
    float* sw = cur;
    cur = nxt;
    nxt = sw;
  }
  k_fc<<<4096, 256, 0, stream>>>(cur, fcw, fcb, out1);
}

// Round 4
// 1298.562 us; speedup vs baseline: 3.2091x; 3.2091x over previous
//
#include <hip/hip_runtime.h>
#include <hip/hip_bf16.h>

// ---------------- scatter: entity GEMM + relu + scatter-add ----------------
// emb [64,512,256] f32, xy [64,512,16] i32, w [32,256] f32 -> scat [64,32,64,64] f32 (pre-zeroed)
__global__ __launch_bounds__(256) void k_scatter(const float* __restrict__ emb,
                                                 const int* __restrict__ xy,
                                                 const float* __restrict__ w,
                                                 float* __restrict__ scat) {
  __shared__ float wl[32 * 257];  // +1 pad: lanes c=0..31 hit distinct banks
  __shared__ float el[8 * 256];
  const int tid = threadIdx.x;
  for (int i = tid; i < 32 * 256; i += 256) {
    int c = i >> 8, d = i & 255;
    wl[c * 257 + d] = w[i];
  }
  const int g0 = blockIdx.x * 8;  // 8 entities per block
  for (int i = tid; i < 2048; i += 256) el[i] = emb[(size_t)g0 * 256 + i];
  __syncthreads();
  const int e = tid >> 5, c = tid & 31;
  const int g = g0 + e;
  const float* er = &el[e << 8];
  const float* wr = &wl[c * 257];
  float acc = 0.f;
#pragma unroll 16
  for (int d = 0; d < 256; ++d) acc += er[d] * wr[d];
  const int* bp = xy + (size_t)g * 16;
  int xv = 0, yv = 0;
#pragma unroll
  for (int j = 0; j < 8; ++j) xv = (xv << 1) | bp[j];
#pragma unroll
  for (int j = 8; j < 16; ++j) yv = (yv << 1) | bp[j];
  const bool valid = (bp[0] != -1000000000);
  float v = acc > 0.f ? acc : 0.f;
  if (valid && v != 0.f) {
    xv >>= 2;
    yv >>= 2;
    const int b = g >> 9;
    atomicAdd(&scat[(((size_t)b * 32 + c) << 12) + (yv << 6) + xv], v);
  }
}

// ---------------- project: concat + 1x1 conv + relu, LDS-tiled ----------------
// block = (b, 128-pixel tile); stage 50x128 inputs + 50x32 weights in LDS; thread = 2 co x 8 pix
__global__ __launch_bounds__(256) void k_proj2(const float* __restrict__ scat,
                                               const float* __restrict__ xin,
                                               const float* __restrict__ pw,
                                               const float* __restrict__ pb,
                                               float* __restrict__ out) {
  __shared__ float sl[50 * 128];
  __shared__ float wlds[50 * 32];
  const int tid = threadIdx.x;
  const int b = blockIdx.x >> 5;
  const int yx0 = (blockIdx.x & 31) << 7;
  for (int i = tid; i < 1600; i += 256) {
    const int co = i / 50, ci = i % 50;
    wlds[ci * 32 + co] = pw[i];
  }
  for (int i = tid; i < 6400; i += 256) {
    const int ci = i >> 7, p = i & 127;
    sl[i] = (ci < 32) ? scat[((size_t)(b * 32 + ci) << 12) + yx0 + p]
                      : xin[(size_t)(b * 18 + ci - 32) * 4096 + yx0 + p];
  }
  __syncthreads();
  const int pix0 = (tid & 15) << 3;
  const int co0 = (tid >> 4) << 1;
  float acc0[8], acc1[8];
  const float b0 = pb[co0], b1 = pb[co0 + 1];
#pragma unroll
  for (int m = 0; m < 8; ++m) { acc0[m] = b0; acc1[m] = b1; }
  for (int ci = 0; ci < 50; ++ci) {
    const float* rp = &sl[(ci << 7) + pix0];
    float rin[8];
#pragma unroll
    for (int j = 0; j < 8; ++j) rin[j] = rp[j];
    const float w0 = wlds[ci * 32 + co0];
    const float w1 = wlds[ci * 32 + co0 + 1];
#pragma unroll
    for (int m = 0; m < 8; ++m) { acc0[m] += w0 * rin[m]; acc1[m] += w1 * rin[m]; }
  }
  float* o0 = out + ((size_t)(b * 32 + co0) << 12) + yx0 + pix0;
  float* o1 = o0 + 4096;
#pragma unroll
  for (int m = 0; m < 8; ++m) {
    o0[m] = acc0[m] > 0.f ? acc0[m] : 0.f;
    o1[m] = acc1[m] > 0.f ? acc1[m] : 0.f;
  }
}

// ---------------- 4x4 stride-2 pad-1 conv + relu, LDS-tiled register-blocked ----------------
// Block: one b, TH output rows, COB output channels. LDS: input halo tile (CIC ci-chunk,
// 2TH+2 rows x HIN+2 cols, zero-padded -> no bounds branches in hot loop) + weights as float4.
// Thread: TM contiguous wo x TN co accumulators; each LDS input row segment feeds TN*TM*4 FMAs.
template <int CIN, int COUT, int HIN, int TH, int CIC, int COB, int TM, int TN>
__global__ __launch_bounds__(256) void k_ds(const float* __restrict__ in,
                                            const float* __restrict__ w,
                                            const float* __restrict__ bias,
                                            float* __restrict__ out) {
  constexpr int HOUT = HIN / 2;
  constexpr int ROWS = 2 * TH + 2;
  constexpr int COLS = HIN + 2;
  constexpr int WG = HOUT / TM;   // wo-groups per row
  constexpr int SPG = TH * WG;    // spatial groups
  constexpr int COG = COB / TN;   // co groups
  constexpr int NCHUNK = CIN / CIC;
  constexpr int NE_IN = CIC * ROWS * COLS;
  constexpr int NE_W = COB * CIC * 4;  // float4 elements
  static_assert(SPG * COG == 256, "thread mapping must cover block");
  __shared__ float lin[NE_IN];
  __shared__ float4 wl[CIC * 4 * COB];
  const int tid = threadIdx.x;
  int bx = blockIdx.x;
  constexpr int NCOB = COUT / COB;
  const int co_blk = bx % NCOB; bx /= NCOB;
  const int ho_blk = bx % (HOUT / TH);
  const int b = bx / (HOUT / TH);
  const int ho0 = ho_blk * TH;
  const int sp = tid % SPG;
  const int dho = sp / WG;
  const int wo0 = (sp % WG) * TM;
  const int co0 = (tid / SPG) * TN;
  float acc[TN][TM];
#pragma unroll
  for (int n = 0; n < TN; ++n) {
    const float bv = bias[co_blk * COB + co0 + n];
#pragma unroll
    for (int m = 0; m < TM; ++m) acc[n][m] = bv;
  }
  const float4* wg4 = (const float4*)w;
  for (int cc = 0; cc < NCHUNK; ++cc) {
    __syncthreads();
    for (int i = tid; i < NE_IN; i += 256) {
      const int ci = i / (ROWS * COLS);
      const int rem = i % (ROWS * COLS);
      const int r = rem / COLS, c = rem % COLS;
      const int hi = 2 * ho0 - 1 + r;
      const int wc = c - 1;
      float v = 0.f;
      if (hi >= 0 && hi < HIN && wc >= 0 && wc < HIN)
        v = in[((size_t)(b * CIN + cc * CIC + ci) * HIN + hi) * HIN + wc];
      lin[i] = v;
    }
    for (int i = tid; i < NE_W; i += 256) {
      const int co = i / (CIC * 4);
      const int rem = i % (CIC * 4);
      const int ci = rem / 4, ky = rem % 4;
      wl[(ci * 4 + ky) * COB + co] =
          wg4[(size_t)((co_blk * COB + co) * CIN + cc * CIC + ci) * 4 + ky];
    }
    __syncthreads();
    for (int ci = 0; ci < CIC; ++ci) {
#pragma unroll
      for (int ky = 0; ky < 4; ++ky) {
        const int r = 2 * dho + ky;
        const float* lr = &lin[(ci * ROWS + r) * COLS + 2 * wo0];
        float rin[2 * TM + 2];
#pragma unroll
        for (int j = 0; j < 2 * TM + 2; ++j) rin[j] = lr[j];
#pragma unroll
        for (int n = 0; n < TN; ++n) {
          const float4 wv = wl[(ci * 4 + ky) * COB + co0 + n];
#pragma unroll
          for (int m = 0; m < TM; ++m)
            acc[n][m] += wv.x * rin[2 * m] + wv.y * rin[2 * m + 1] +
                         wv.z * rin[2 * m + 2] + wv.w * rin[2 * m + 3];
        }
      }
    }
  }
  const int ho = ho0 + dho;
#pragma unroll
  for (int n = 0; n < TN; ++n)
#pragma unroll
    for (int m = 0; m < TM; ++m) {
      const float v = acc[n][m];
      out[((size_t)(b * COUT + co_blk * COB + co0 + n) * HOUT + ho) * HOUT + wo0 + m] =
          v > 0.f ? v : 0.f;
    }
}

// ---------------- 3x3 pad-1 conv on 8x8, fused batch-stat accumulation ----------------
__global__ __launch_bounds__(256) void k_resconv(const float* __restrict__ in,
                                                 const float* __restrict__ wf,
                                                 float* __restrict__ out,
                                                 float* __restrict__ stats) {
  __shared__ float lin[12800];  // 128 ch * 100 (10x10 halo)
  const int tid = threadIdx.x;
  const int b = blockIdx.x >> 3;              // 8 blocks per b
  const int co_base = (blockIdx.x & 7) << 4;  // 16 co per block
  for (int i = tid; i < 12800; i += 256) lin[i] = 0.f;
  __syncthreads();
  const float* ib = in + (size_t)b * 8192;
  for (int i = tid; i < 8192; i += 256) {
    const int ci = i >> 6, p = i & 63;
    lin[ci * 100 + ((p >> 3) + 1) * 10 + (p & 7) + 1] = ib[i];
  }
  __syncthreads();
  const int wq = __builtin_amdgcn_readfirstlane((int)(tid >> 6));  // force wave-uniform
  const int lane = tid & 63;
  const int co0 = co_base + wq * 4;
  const int ho = lane >> 3, wo = lane & 7;
  float a0 = 0.f, a1 = 0.f, a2 = 0.f, a3 = 0.f;
  const float* wbase = wf + (size_t)co0 * 1152;  // uniform -> scalar loads
  for (int ci = 0; ci < 128; ++ci) {
    const float* lp = &lin[ci * 100 + ho * 10 + wo];
    const float r0 = lp[0], r1 = lp[1], r2 = lp[2];
    const float r3 = lp[10], r4 = lp[11], r5 = lp[12];
    const float r6 = lp[20], r7 = lp[21], r8 = lp[22];
    const float* w0 = wbase + ci * 9;
    const float* w1 = w0 + 1152;
    const float* w2 = w0 + 2304;
    const float* w3 = w0 + 3456;
    a0 += w0[0] * r0 + w0[1] * r1 + w0[2] * r2 + w0[3] * r3 + w0[4] * r4 +
          w0[5] * r5 + w0[6] * r6 + w0[7] * r7 + w0[8] * r8;
    a1 += w1[0] * r0 + w1[1] * r1 + w1[2] * r2 + w1[3] * r3 + w1[4] * r4 +
          w1[5] * r5 + w1[6] * r6 + w1[7] * r7 + w1[8] * r8;
    a2 += w2[0] * r0 + w2[1] * r1 + w2[2] * r2 + w2[3] * r3 + w2[4] * r4 +
          w2[5] * r5 + w2[6] * r6 + w2[7] * r7 + w2[8] * r8;
    a3 += w3[0] * r0 + w3[1] * r1 + w3[2] * r2 + w3[3] * r3 + w3[4] * r4 +
          w3[5] * r5 + w3[6] * r6 + w3[7] * r7 + w3[8] * r8;
  }
  const size_t ob = ((size_t)b * 128 + co0) * 64 + lane;
  out[ob] = a0;
  out[ob + 64] = a1;
  out[ob + 128] = a2;
  out[ob + 192] = a3;
  float sv[4] = {a0, a1, a2, a3};
#pragma unroll
  for (int j = 0; j < 4; ++j) {
    float s = sv[j], q = sv[j] * sv[j];
#pragma unroll
    for (int off = 32; off > 0; off >>= 1) {
      s += __shfl_down(s, off);
      q += __shfl_down(q, off);
    }
    if (lane == 0) {
      atomicAdd(&stats[co0 + j], s);
      atomicAdd(&stats[128 + co0 + j], q);
    }
  }
}

// ---------------- BN (batch stats) + relu ----------------
__global__ __launch_bounds__(256) void k_bnrelu(const float* __restrict__ in,
                                                const float* __restrict__ stats,
                                                const float* __restrict__ g,
                                                const float* __restrict__ bb,
                                                float* __restrict__ out) {
  const int idx = blockIdx.x * 256 + threadIdx.x;  // 524288
  const int co = (idx >> 6) & 127;
  const float mu = stats[co] * (1.f / 4096.f);
  const float var = stats[128 + co] * (1.f / 4096.f) - mu * mu;
  const float v = g[co] * (in[idx] - mu) * rsqrtf(var + 1e-5f) + bb[co];
  out[idx] = v > 0.f ? v : 0.f;
}

// ---------------- BN + residual add + relu + map_skip accumulate ----------------
__global__ __launch_bounds__(256) void k_bnadd(const float* __restrict__ in,
                                               const float* __restrict__ stats,
                                               const float* __restrict__ g,
                                               const float* __restrict__ bb,
                                               const float* __restrict__ ident,
                                               float* __restrict__ hout,
                                               float* __restrict__ ms) {
  const int idx = blockIdx.x * 256 + threadIdx.x;
  const int co = (idx >> 6) & 127;
  const float mu = stats[co] * (1.f / 4096.f);
  const float var = stats[128 + co] * (1.f / 4096.f) - mu * mu;
  float v = g[co] * (in[idx] - mu) * rsqrtf(var + 1e-5f) + bb[co];
  v += ident[idx];
  v = v > 0.f ? v : 0.f;
  hout[idx] = v;
  ms[idx] += v;
}

__global__ __launch_bounds__(256) void k_copy(const float* __restrict__ a,
                                              float* __restrict__ b) {
  const int i = blockIdx.x * 256 + threadIdx.x;
  b[i] = a[i];
}

// ---------------- FC: [64,8192] x [256,8192]^T + b, relu -> f32 out ----------------
__global__ __launch_bounds__(256) void k_fc(const float* __restrict__ h,
                                            const float* __restrict__ w,
                                            const float* __restrict__ bias,
                                            float* __restrict__ out) {
  const int wid = blockIdx.x * 4 + (threadIdx.x >> 6);
  const int lane = threadIdx.x & 63;
  const int b = wid >> 8, j = wid & 255;
  const float* hp = h + ((size_t)b << 13);
  const float* wp = w + ((size_t)j << 13);
  float acc = 0.f;
  for (int k = lane; k < 8192; k += 64) acc += hp[k] * wp[k];
#pragma unroll
  for (int off = 32; off > 0; off >>= 1) acc += __shfl_down(acc, off);
  if (lane == 0) {
    float v = acc + bias[j];
    out[b * 256 + j] = v > 0.f ? v : 0.f;
  }
}

extern "C" void kernel_launch(void* const* d_in, const int* in_sizes, int n_in,
                              void* d_out, int out_size, void* d_ws, size_t ws_size,
                              hipStream_t stream) {
  const float* xin = (const float*)d_in[0];
  const float* emb = (const float*)d_in[1];
  const int* xy = (const int*)d_in[2];
  const float* c1w = (const float*)d_in[3];
  const float* pw = (const float*)d_in[4];
  const float* pb = (const float*)d_in[5];
  const float* d1w = (const float*)d_in[6];
  const float* d1b = (const float*)d_in[7];
  const float* d2w = (const float*)d_in[8];
  const float* d2b = (const float*)d_in[9];
  const float* d3w = (const float*)d_in[10];
  const float* d3b = (const float*)d_in[11];
  const float* rc1w = (const float*)d_in[12];
  const float* rbn1g = (const float*)d_in[13];
  const float* rbn1b = (const float*)d_in[14];
  const float* rc2w = (const float*)d_in[15];
  const float* rbn2g = (const float*)d_in[16];
  const float* rbn2b = (const float*)d_in[17];
  const float* fcw = (const float*)d_in[18];
  const float* fcb = (const float*)d_in[19];

  float* out0 = (float*)d_out;          // map_skip [64,128,8,8] f32
  float* out1 = out0 + 524288;          // embedded_spatial [64,256] f32

  float* F = (float*)d_ws;
  float* scat = F + 0;                  // 8388608  [B,32,64,64]
  float* h0 = F + 8388608;              // 8388608  [B,32,64,64]
  float* h1 = F + 0;                    // 4194304  [B,64,32,32]   (reuses scat)
  float* h2 = F + 4194304;              // 2097152  [B,128,16,16]
  float* hA = F + 6291456;              // 524288   h ping
  float* hB = F + 6815744;              // 524288   h pong
  float* tmp = F + 7340032;             // 524288   conv pre-BN
  float* obuf = F + 7864320;            // 524288   post-BN1
  float* stats = F + 17956864;          // 2048     8 x {sum[128],sumsq[128]}

  hipMemsetAsync(scat, 0, 8388608 * sizeof(float), stream);
  hipMemsetAsync(stats, 0, 2048 * sizeof(float), stream);

  k_scatter<<<4096, 256, 0, stream>>>(emb, xy, c1w, scat);
  k_proj2<<<2048, 256, 0, stream>>>(scat, xin, pw, pb, h0);
  // ds1: 32->64 ch, 64->32 spatial.  grid = B * (32/4) * (64/64) = 512
  k_ds<32, 64, 64, 4, 8, 64, 8, 4><<<512, 256, 0, stream>>>(h0, d1w, d1b, h1);
  // ds2: 64->128 ch, 32->16 spatial. grid = B * (16/4) * (128/64) = 512
  k_ds<64, 128, 32, 4, 8, 64, 8, 2><<<512, 256, 0, stream>>>(h1, d2w, d2b, h2);
  // ds3: 128->128 ch, 16->8 spatial. grid = B * (8/8) * (128/32) = 256
  k_ds<128, 128, 16, 8, 8, 32, 4, 2><<<256, 256, 0, stream>>>(h2, d3w, d3b, hA);
  k_copy<<<2048, 256, 0, stream>>>(hA, out0);  // map_skip accumulator in d_out (f32)

  float* cur = hA;
  float* nxt = hB;
  for (int i = 0; i < 4; ++i) {
    float* sA = stats + i * 512;
    float* sB = stats + i * 512 + 256;
    k_resconv<<<512, 256, 0, stream>>>(cur, rc1w + (size_t)i * 147456, tmp, sA);
    k_bnrelu<<<2048, 256, 0, stream>>>(tmp, sA, rbn1g + i * 128, rbn1b + i * 128, obuf);
    k_resconv<<<512, 256, 0, stream>>>(obuf, rc2w + (size_t)i * 147456, tmp, sB);
    k_bnadd<<<2048, 256, 0, stream>>>(tmp, sB, rbn2g + i * 128, rbn2b + i * 128, cur, nxt, out0);
    float* sw = cur;
    cur = nxt;
    nxt = sw;
  }
  k_fc<<<4096, 256, 0, stream>>>(cur, fcw, fcb, out1);
}

// Round 5
// 758.345 us; speedup vs baseline: 5.4951x; 1.7124x over previous
//
#include <hip/hip_runtime.h>
#include <hip/hip_bf16.h>

typedef __attribute__((ext_vector_type(8))) short bf16x8;  // 8 bf16 (4 VGPRs)
typedef __attribute__((ext_vector_type(4))) float f32x4;   // MFMA C/D frag

__device__ __forceinline__ short f2bs(float v) {
  __hip_bfloat16 h = __float2bfloat16(v);
  return *reinterpret_cast<short*>(&h);
}

// ---------- weight transforms: [co][ci][kh][kw] f32 -> [tap][co][ci] bf16 ----------
__global__ __launch_bounds__(256) void k_wtres(const float* __restrict__ src,
                                               short* __restrict__ dst) {
  const int i = blockIdx.x * 256 + threadIdx.x;  // 4 layers * 9 * 128 * 128
  if (i >= 589824) return;
  const int layer = i / 147456;
  const int rem = i % 147456;
  const int tap = rem / 16384;
  const int r2 = rem & 16383;
  const int co = r2 >> 7, ci = r2 & 127;
  dst[i] = f2bs(src[(((size_t)layer * 16384 + co * 128 + ci) * 9) + tap]);
}

template <int CIN, int COUT>
__global__ __launch_bounds__(256) void k_wtds(const float* __restrict__ src,
                                              short* __restrict__ dst) {
  const int i = blockIdx.x * 256 + threadIdx.x;  // 16 * COUT * CIN
  if (i >= 16 * COUT * CIN) return;
  const int tap = i / (COUT * CIN);
  const int rem = i % (COUT * CIN);
  const int co = rem / CIN, ci = rem % CIN;
  dst[i] = f2bs(src[((size_t)(co * CIN + ci)) * 16 + tap]);
}

// ---------------- scatter: entity GEMM + relu + scatter-add (unchanged) ----------------
__global__ __launch_bounds__(256) void k_scatter(const float* __restrict__ emb,
                                                 const int* __restrict__ xy,
                                                 const float* __restrict__ w,
                                                 float* __restrict__ scat) {
  __shared__ float wl[32 * 257];
  __shared__ float el[8 * 256];
  const int tid = threadIdx.x;
  for (int i = tid; i < 32 * 256; i += 256) {
    int c = i >> 8, d = i & 255;
    wl[c * 257 + d] = w[i];
  }
  const int g0 = blockIdx.x * 8;
  for (int i = tid; i < 2048; i += 256) el[i] = emb[(size_t)g0 * 256 + i];
  __syncthreads();
  const int e = tid >> 5, c = tid & 31;
  const int g = g0 + e;
  const float* er = &el[e << 8];
  const float* wr = &wl[c * 257];
  float acc = 0.f;
#pragma unroll 16
  for (int d = 0; d < 256; ++d) acc += er[d] * wr[d];
  const int* bp = xy + (size_t)g * 16;
  int xv = 0, yv = 0;
#pragma unroll
  for (int j = 0; j < 8; ++j) xv = (xv << 1) | bp[j];
#pragma unroll
  for (int j = 8; j < 16; ++j) yv = (yv << 1) | bp[j];
  const bool valid = (bp[0] != -1000000000);
  float v = acc > 0.f ? acc : 0.f;
  if (valid && v != 0.f) {
    xv >>= 2;
    yv >>= 2;
    const int b = g >> 9;
    atomicAdd(&scat[(((size_t)b * 32 + c) << 12) + (yv << 6) + xv], v);
  }
}

// ---------------- project: concat + 1x1 conv + relu, LDS-tiled (unchanged) ----------------
__global__ __launch_bounds__(256) void k_proj2(const float* __restrict__ scat,
                                               const float* __restrict__ xin,
                                               const float* __restrict__ pw,
                                               const float* __restrict__ pb,
                                               float* __restrict__ out) {
  __shared__ float sl[50 * 128];
  __shared__ float wlds[50 * 32];
  const int tid = threadIdx.x;
  const int b = blockIdx.x >> 5;
  const int yx0 = (blockIdx.x & 31) << 7;
  for (int i = tid; i < 1600; i += 256) {
    const int co = i / 50, ci = i % 50;
    wlds[ci * 32 + co] = pw[i];
  }
  for (int i = tid; i < 6400; i += 256) {
    const int ci = i >> 7, p = i & 127;
    sl[i] = (ci < 32) ? scat[((size_t)(b * 32 + ci) << 12) + yx0 + p]
                      : xin[(size_t)(b * 18 + ci - 32) * 4096 + yx0 + p];
  }
  __syncthreads();
  const int pix0 = (tid & 15) << 3;
  const int co0 = (tid >> 4) << 1;
  float acc0[8], acc1[8];
  const float b0 = pb[co0], b1 = pb[co0 + 1];
#pragma unroll
  for (int m = 0; m < 8; ++m) { acc0[m] = b0; acc1[m] = b1; }
  for (int ci = 0; ci < 50; ++ci) {
    const float* rp = &sl[(ci << 7) + pix0];
    float rin[8];
#pragma unroll
    for (int j = 0; j < 8; ++j) rin[j] = rp[j];
    const float w0 = wlds[ci * 32 + co0];
    const float w1 = wlds[ci * 32 + co0 + 1];
#pragma unroll
    for (int m = 0; m < 8; ++m) { acc0[m] += w0 * rin[m]; acc1[m] += w1 * rin[m]; }
  }
  float* o0 = out + ((size_t)(b * 32 + co0) << 12) + yx0 + pix0;
  float* o1 = o0 + 4096;
#pragma unroll
  for (int m = 0; m < 8; ++m) {
    o0[m] = acc0[m] > 0.f ? acc0[m] : 0.f;
    o1[m] = acc1[m] > 0.f ? acc1[m] : 0.f;
  }
}

// ---------------- 4x4 s2 p1 conv + bias + relu via MFMA tap-decomposition ----------------
// Block: (b, 2 output rows). M = 2*HOUT pixels (MT m-tiles), N = COUT (NT tiles/wave).
// LDS halo [6][HIN+2][CIPAD] bf16 pixel-major: A-frag = 1 contiguous ds_read_b128.
// wT[tap][co][ci] bf16: B-frag = 1 global 16B load (L1/L2-cached, reused by all blocks).
template <int CIN, int COUT, int HIN, int CIPAD, int MT, int NT, bool STORE2>
__global__ __launch_bounds__(256) void k_dsmfma(const float* __restrict__ in,
                                                const short* __restrict__ wT,
                                                const float* __restrict__ bias,
                                                float* __restrict__ out,
                                                float* __restrict__ out2) {
  constexpr int HOUT = HIN / 2;
  constexpr int COLS = HIN + 2;
  constexpr int KK = CIN / 32;
  constexpr int NE = 6 * CIN * COLS;
  __shared__ short lin[6 * COLS * CIPAD];
  const int tid = threadIdx.x;
  const int hoblk = blockIdx.x % (HOUT / 2);
  const int b = blockIdx.x / (HOUT / 2);
  for (int i = tid; i < NE; i += 256) {
    const int r = i / (CIN * COLS);
    const int rem = i % (CIN * COLS);
    const int ci = rem / COLS;
    const int c = rem % COLS;
    const int hi = 4 * hoblk - 1 + r;
    const int wc = c - 1;
    float v = 0.f;
    if (hi >= 0 && hi < HIN && wc >= 0 && wc < HIN)
      v = in[((size_t)(b * CIN + ci) * HIN + hi) * HIN + wc];
    lin[(r * COLS + c) * CIPAD + ci] = f2bs(v);
  }
  __syncthreads();
  const int wq = __builtin_amdgcn_readfirstlane(tid >> 6);
  const int lane = tid & 63;
  const int l15 = lane & 15;
  const int quad = lane >> 4;
  const int mtile = wq % MT;
  const int cobase = (wq / MT) * (NT * 16);
  const int p = mtile * 16 + l15;  // A-side pixel for this lane
  const int dr = p / HOUT;
  const int col = p % HOUT;
  f32x4 acc[NT];
#pragma unroll
  for (int n = 0; n < NT; ++n) acc[n] = (f32x4){0.f, 0.f, 0.f, 0.f};
  const short* wrow = wT + (size_t)(cobase + l15) * CIN + quad * 8;
  for (int ky = 0; ky < 4; ++ky) {
    for (int kx = 0; kx < 4; ++kx) {
      const short* arow = &lin[((2 * dr + ky) * COLS + 2 * col + kx) * CIPAD + quad * 8];
      const short* wt = wrow + (size_t)(ky * 4 + kx) * COUT * CIN;
#pragma unroll
      for (int kk = 0; kk < KK; ++kk) {
        bf16x8 a = *(const bf16x8*)(arow + kk * 32);
#pragma unroll
        for (int n = 0; n < NT; ++n) {
          bf16x8 bf = *(const bf16x8*)(wt + n * 16 * CIN + kk * 32);
          acc[n] = __builtin_amdgcn_mfma_f32_16x16x32_bf16(a, bf, acc[n], 0, 0, 0);
        }
      }
    }
  }
#pragma unroll
  for (int n = 0; n < NT; ++n) {
    const int co = cobase + n * 16 + l15;
    const float bv = bias[co];
#pragma unroll
    for (int r = 0; r < 4; ++r) {
      const int pp = mtile * 16 + quad * 4 + r;  // D-side pixel (m = quad*4+reg)
      const int dr2 = pp / HOUT;
      const int c2 = pp % HOUT;
      const int ho = hoblk * 2 + dr2;
      float v = acc[n][r] + bv;
      v = v > 0.f ? v : 0.f;
      const size_t o = ((size_t)(b * COUT + co) * HOUT + ho) * HOUT + c2;
      out[o] = v;
      if (STORE2) out2[o] = v;
    }
  }
}

// ---------------- 3x3 s1 p1 conv on 8x8 via MFMA + fused batch stats ----------------
// Block: (b, co-half 64). M = 64 pixels (wave = m-tile), NT=4 n-tiles/wave.
__global__ __launch_bounds__(256) void k_resmfma(const float* __restrict__ in,
                                                 const short* __restrict__ wT,
                                                 float* __restrict__ out,
                                                 float* __restrict__ stats) {
  constexpr int CIPAD = 160;
  __shared__ short lin[100 * CIPAD];  // 10x10 halo, pixel-major, bf16
  const int tid = threadIdx.x;
  const int b = blockIdx.x >> 1;
  const int cobase = (blockIdx.x & 1) * 64;
  for (int i = tid; i < 12800; i += 256) {
    const int ci = i / 100;
    const int rem = i % 100;
    const int r = rem / 10, c = rem % 10;
    float v = 0.f;
    if (r >= 1 && r <= 8 && c >= 1 && c <= 8)
      v = in[((size_t)(b * 128 + ci) << 6) + (r - 1) * 8 + (c - 1)];
    lin[(r * 10 + c) * CIPAD + ci] = f2bs(v);
  }
  __syncthreads();
  const int wq = __builtin_amdgcn_readfirstlane(tid >> 6);
  const int lane = tid & 63;
  const int l15 = lane & 15, quad = lane >> 4;
  const int p = wq * 16 + l15;  // A-side pixel
  const int py = p >> 3, px = p & 7;
  f32x4 acc[4];
#pragma unroll
  for (int n = 0; n < 4; ++n) acc[n] = (f32x4){0.f, 0.f, 0.f, 0.f};
  const short* wrow = wT + (size_t)(cobase + l15) * 128 + quad * 8;
  for (int t = 0; t < 9; ++t) {
    const int ky = t / 3, kx = t % 3;
    const short* arow = &lin[((py + ky) * 10 + px + kx) * CIPAD + quad * 8];
    const short* wt = wrow + (size_t)t * 16384;
#pragma unroll
    for (int kk = 0; kk < 4; ++kk) {
      bf16x8 a = *(const bf16x8*)(arow + kk * 32);
#pragma unroll
      for (int n = 0; n < 4; ++n) {
        bf16x8 bf = *(const bf16x8*)(wt + n * 16 * 128 + kk * 32);
        acc[n] = __builtin_amdgcn_mfma_f32_16x16x32_bf16(a, bf, acc[n], 0, 0, 0);
      }
    }
  }
  float* ob = out + ((size_t)b << 13);
#pragma unroll
  for (int n = 0; n < 4; ++n) {
    const int co = cobase + n * 16 + l15;
    float s = 0.f, q = 0.f;
#pragma unroll
    for (int r = 0; r < 4; ++r) {
      const float v = acc[n][r];
      ob[((size_t)co << 6) + wq * 16 + quad * 4 + r] = v;
      s += v;
      q += v * v;
    }
    s += __shfl_down(s, 32); q += __shfl_down(q, 32);
    s += __shfl_down(s, 16); q += __shfl_down(q, 16);
    if (lane < 16) {
      atomicAdd(&stats[co], s);
      atomicAdd(&stats[128 + co], q);
    }
  }
}

// ---------------- BN (batch stats) + relu ----------------
__global__ __launch_bounds__(256) void k_bnrelu(const float* __restrict__ in,
                                                const float* __restrict__ stats,
                                                const float* __restrict__ g,
                                                const float* __restrict__ bb,
                                                float* __restrict__ out) {
  const int idx = blockIdx.x * 256 + threadIdx.x;
  const int co = (idx >> 6) & 127;
  const float mu = stats[co] * (1.f / 4096.f);
  const float var = stats[128 + co] * (1.f / 4096.f) - mu * mu;
  const float v = g[co] * (in[idx] - mu) * rsqrtf(var + 1e-5f) + bb[co];
  out[idx] = v > 0.f ? v : 0.f;
}

// ---------------- BN + residual add + relu + map_skip accumulate ----------------
__global__ __launch_bounds__(256) void k_bnadd(const float* __restrict__ in,
                                               const float* __restrict__ stats,
                                               const float* __restrict__ g,
                                               const float* __restrict__ bb,
                                               const float* __restrict__ ident,
                                               float* __restrict__ hout,
                                               float* __restrict__ ms) {
  const int idx = blockIdx.x * 256 + threadIdx.x;
  const int co = (idx >> 6) & 127;
  const float mu = stats[co] * (1.f / 4096.f);
  const float var = stats[128 + co] * (1.f / 4096.f) - mu * mu;
  float v = g[co] * (in[idx] - mu) * rsqrtf(var + 1e-5f) + bb[co];
  v += ident[idx];
  v = v > 0.f ? v : 0.f;
  hout[idx] = v;
  ms[idx] += v;
}

// ---------------- FC: [64,8192] x [256,8192]^T + b, relu -> f32 out ----------------
__global__ __launch_bounds__(256) void k_fc(const float* __restrict__ h,
                                            const float* __restrict__ w,
                                            const float* __restrict__ bias,
                                            float* __restrict__ out) {
  const int wid = blockIdx.x * 4 + (threadIdx.x >> 6);
  const int lane = threadIdx.x & 63;
  const int b = wid >> 8, j = wid & 255;
  const float* hp = h + ((size_t)b << 13);
  const float* wp = w + ((size_t)j << 13);
  float acc = 0.f;
  for (int k = lane; k < 8192; k += 64) acc += hp[k] * wp[k];
#pragma unroll
  for (int off = 32; off > 0; off >>= 1) acc += __shfl_down(acc, off);
  if (lane == 0) {
    float v = acc + bias[j];
    out[b * 256 + j] = v > 0.f ? v : 0.f;
  }
}

extern "C" void kernel_launch(void* const* d_in, const int* in_sizes, int n_in,
                              void* d_out, int out_size, void* d_ws, size_t ws_size,
                              hipStream_t stream) {
  const float* xin = (const float*)d_in[0];
  const float* emb = (const float*)d_in[1];
  const int* xy = (const int*)d_in[2];
  const float* c1w = (const float*)d_in[3];
  const float* pw = (const float*)d_in[4];
  const float* pb = (const float*)d_in[5];
  const float* d1w = (const float*)d_in[6];
  const float* d1b = (const float*)d_in[7];
  const float* d2w = (const float*)d_in[8];
  const float* d2b = (const float*)d_in[9];
  const float* d3w = (const float*)d_in[10];
  const float* d3b = (const float*)d_in[11];
  const float* rc1w = (const float*)d_in[12];
  const float* rbn1g = (const float*)d_in[13];
  const float* rbn1b = (const float*)d_in[14];
  const float* rc2w = (const float*)d_in[15];
  const float* rbn2g = (const float*)d_in[16];
  const float* rbn2b = (const float*)d_in[17];
  const float* fcw = (const float*)d_in[18];
  const float* fcb = (const float*)d_in[19];

  float* out0 = (float*)d_out;   // map_skip [64,128,8,8] f32
  float* out1 = out0 + 524288;   // embedded_spatial [64,256] f32

  float* F = (float*)d_ws;
  float* scat = F + 0;           // [0, 8388608)
  float* h0 = F + 8388608;       // [8388608, 16777216)  dead after ds1
  float* h1 = F + 0;             // reuses scat
  float* h2 = F + 4194304;
  float* hA = F + 6291456;
  float* hB = F + 6815744;
  float* tmp = F + 7340032;
  float* obuf = F + 7864320;     // ends 8388608
  float* stats = F + 8388608;    // 2048 floats, carved from h0 AFTER ds1 consumes it
  short* wTr1 = (short*)(F + 16777216);   // 4*9*128*128 bf16
  short* wTr2 = wTr1 + 589824;
  short* wTds1 = wTr2 + 589824;           // 16*64*32
  short* wTds2 = wTds1 + 32768;           // 16*128*64
  short* wTds3 = wTds2 + 131072;          // 16*128*128; ends at 70.3 MB total

  hipMemsetAsync(scat, 0, 8388608 * sizeof(float), stream);
  k_wtres<<<2304, 256, 0, stream>>>(rc1w, wTr1);
  k_wtres<<<2304, 256, 0, stream>>>(rc2w, wTr2);
  k_wtds<32, 64><<<128, 256, 0, stream>>>(d1w, wTds1);
  k_wtds<64, 128><<<512, 256, 0, stream>>>(d2w, wTds2);
  k_wtds<128, 128><<<1024, 256, 0, stream>>>(d3w, wTds3);

  k_scatter<<<4096, 256, 0, stream>>>(emb, xy, c1w, scat);
  k_proj2<<<2048, 256, 0, stream>>>(scat, xin, pw, pb, h0);
  // ds1: grid = 64 b * 16 ho-blocks; MT=4 mtiles, NT=4 (co 0..63)
  k_dsmfma<32, 64, 64, 48, 4, 4, false><<<1024, 256, 0, stream>>>(h0, wTds1, d1b, h1, h1);
  hipMemsetAsync(stats, 0, 2048 * sizeof(float), stream);  // h0 dead from here
  // ds2: grid = 64 * 8; MT=2, NT=4 (wave -> co-half)
  k_dsmfma<64, 128, 32, 80, 2, 4, false><<<512, 256, 0, stream>>>(h1, wTds2, d2b, h2, h2);
  // ds3: grid = 64 * 4; MT=1, NT=2 (wave -> co-quarter); dual-store seeds map_skip
  k_dsmfma<128, 128, 16, 144, 1, 2, true><<<256, 256, 0, stream>>>(h2, wTds3, d3b, hA, out0);

  float* cur = hA;
  float* nxt = hB;
  for (int i = 0; i < 4; ++i) {
    float* sA = stats + i * 512;
    float* sB = stats + i * 512 + 256;
    k_resmfma<<<128, 256, 0, stream>>>(cur, wTr1 + (size_t)i * 147456, tmp, sA);
    k_bnrelu<<<2048, 256, 0, stream>>>(tmp, sA, rbn1g + i * 128, rbn1b + i * 128, obuf);
    k_resmfma<<<128, 256, 0, stream>>>(obuf, wTr2 + (size_t)i * 147456, tmp, sB);
    k_bnadd<<<2048, 256, 0, stream>>>(tmp, sB, rbn2g + i * 128, rbn2b + i * 128, cur, nxt, out0);
    float* sw = cur;
    cur = nxt;
    nxt = sw;
  }
  k_fc<<<4096, 256, 0, stream>>>(cur, fcw, fcb, out1);
}

// Round 6
// 516.198 us; speedup vs baseline: 8.0729x; 1.4691x over previous
//
#include <hip/hip_runtime.h>
#include <hip/hip_bf16.h>

typedef __attribute__((ext_vector_type(8))) short bf16x8;  // 8 bf16 (4 VGPRs)
typedef __attribute__((ext_vector_type(4))) float f32x4;   // MFMA C/D frag

__device__ __forceinline__ short f2bs(float v) {
  __hip_bfloat16 h = __float2bfloat16(v);
  return *reinterpret_cast<short*>(&h);
}

// ---------- weight transforms: [co][ci][kh][kw] f32 -> [tap][co][ci] bf16 ----------
__global__ __launch_bounds__(256) void k_wtres(const float* __restrict__ src,
                                               short* __restrict__ dst) {
  const int i = blockIdx.x * 256 + threadIdx.x;  // 4 layers * 9 * 128 * 128
  if (i >= 589824) return;
  const int layer = i / 147456;
  const int rem = i % 147456;
  const int tap = rem / 16384;
  const int r2 = rem & 16383;
  const int co = r2 >> 7, ci = r2 & 127;
  dst[i] = f2bs(src[(((size_t)layer * 16384 + co * 128 + ci) * 9) + tap]);
}

template <int CIN, int COUT>
__global__ __launch_bounds__(256) void k_wtds(const float* __restrict__ src,
                                              short* __restrict__ dst) {
  const int i = blockIdx.x * 256 + threadIdx.x;  // 16 * COUT * CIN
  if (i >= 16 * COUT * CIN) return;
  const int tap = i / (COUT * CIN);
  const int rem = i % (COUT * CIN);
  const int co = rem / CIN, ci = rem % CIN;
  dst[i] = f2bs(src[((size_t)(co * CIN + ci)) * 16 + tap]);
}

// ---------- fc weight: [j][co*64+pix] f32 -> [j][pix*128+co] bf16 (block per j) ----------
__global__ __launch_bounds__(256) void k_wfc(const float* __restrict__ src,
                                             short* __restrict__ dst) {
  __shared__ float ld[128 * 65];
  const int j = blockIdx.x;
  const int tid = threadIdx.x;
  const float* sp = src + (size_t)j * 8192;
  for (int i = tid; i < 8192; i += 256) {
    const int co = i >> 6, pix = i & 63;
    ld[co * 65 + pix] = sp[i];
  }
  __syncthreads();
  short* dp = dst + (size_t)j * 8192;
  for (int i = tid; i < 8192; i += 256) {
    const int pix = i >> 7, co = i & 127;
    dp[i] = f2bs(ld[co * 65 + pix]);
  }
}

// ---------------- scatter: entity GEMM + relu + scatter-add (32 entities/block) ----------------
__global__ __launch_bounds__(256) void k_scatter(const float* __restrict__ emb,
                                                 const int* __restrict__ xy,
                                                 const float* __restrict__ w,
                                                 float* __restrict__ scat) {
  __shared__ float wl[32 * 257];
  __shared__ float el[32 * 256];
  const int tid = threadIdx.x;
  for (int i = tid; i < 32 * 256; i += 256) {
    int c = i >> 8, d = i & 255;
    wl[c * 257 + d] = w[i];
  }
  const int g0 = blockIdx.x * 32;
  for (int i = tid; i < 8192; i += 256) el[i] = emb[(size_t)g0 * 256 + i];
  __syncthreads();
  const int e0 = tid >> 5, c = tid & 31;
  const float* wr = &wl[c * 257];
#pragma unroll
  for (int t = 0; t < 4; ++t) {
    const int e = e0 + t * 8;
    const int g = g0 + e;
    const float* er = &el[e << 8];
    float acc = 0.f;
#pragma unroll 16
    for (int d = 0; d < 256; ++d) acc += er[d] * wr[d];
    const int* bp = xy + (size_t)g * 16;
    int xv = 0, yv = 0;
#pragma unroll
    for (int j = 0; j < 8; ++j) xv = (xv << 1) | bp[j];
#pragma unroll
    for (int j = 8; j < 16; ++j) yv = (yv << 1) | bp[j];
    const bool valid = (bp[0] != -1000000000);
    float v = acc > 0.f ? acc : 0.f;
    if (valid && v != 0.f) {
      const int b = g >> 9;
      atomicAdd(&scat[(((size_t)b * 32 + c) << 12) + ((yv >> 2) << 6) + (xv >> 2)], v);
    }
  }
}

// ---------------- project: concat + 1x1 conv + relu, LDS-tiled ----------------
__global__ __launch_bounds__(256) void k_proj2(const float* __restrict__ scat,
                                               const float* __restrict__ xin,
                                               const float* __restrict__ pw,
                                               const float* __restrict__ pb,
                                               float* __restrict__ out) {
  __shared__ float sl[50 * 128];
  __shared__ float wlds[50 * 32];
  const int tid = threadIdx.x;
  const int b = blockIdx.x >> 5;
  const int yx0 = (blockIdx.x & 31) << 7;
  for (int i = tid; i < 1600; i += 256) {
    const int co = i / 50, ci = i % 50;
    wlds[ci * 32 + co] = pw[i];
  }
  for (int i = tid; i < 6400; i += 256) {
    const int ci = i >> 7, p = i & 127;
    sl[i] = (ci < 32) ? scat[((size_t)(b * 32 + ci) << 12) + yx0 + p]
                      : xin[(size_t)(b * 18 + ci - 32) * 4096 + yx0 + p];
  }
  __syncthreads();
  const int pix0 = (tid & 15) << 3;
  const int co0 = (tid >> 4) << 1;
  float acc0[8], acc1[8];
  const float b0 = pb[co0], b1 = pb[co0 + 1];
#pragma unroll
  for (int m = 0; m < 8; ++m) { acc0[m] = b0; acc1[m] = b1; }
  for (int ci = 0; ci < 50; ++ci) {
    const float* rp = &sl[(ci << 7) + pix0];
    float rin[8];
#pragma unroll
    for (int j = 0; j < 8; ++j) rin[j] = rp[j];
    const float w0 = wlds[ci * 32 + co0];
    const float w1 = wlds[ci * 32 + co0 + 1];
#pragma unroll
    for (int m = 0; m < 8; ++m) { acc0[m] += w0 * rin[m]; acc1[m] += w1 * rin[m]; }
  }
  float* o0 = out + ((size_t)(b * 32 + co0) << 12) + yx0 + pix0;
  float* o1 = o0 + 4096;
#pragma unroll
  for (int m = 0; m < 8; ++m) {
    o0[m] = acc0[m] > 0.f ? acc0[m] : 0.f;
    o1[m] = acc1[m] > 0.f ? acc1[m] : 0.f;
  }
}

// ---------------- 4x4 s2 p1 conv + bias + relu via MFMA tap-decomposition ----------------
// OUTMODE 0: canonical f32 [b][co][ho][wo]. OUTMODE 1 (HOUT==8): pixel-major triple
// (out=h_pm f32, out2=ms_pm f32, outbf=h_pm bf16).
template <int CIN, int COUT, int HIN, int CIPAD, int MT, int NT, int OUTMODE>
__global__ __launch_bounds__(256) void k_dsmfma(const float* __restrict__ in,
                                                const short* __restrict__ wT,
                                                const float* __restrict__ bias,
                                                float* __restrict__ out,
                                                float* __restrict__ out2,
                                                short* __restrict__ outbf) {
  constexpr int HOUT = HIN / 2;
  constexpr int COLS = HIN + 2;
  constexpr int KK = CIN / 32;
  constexpr int NE = 6 * CIN * COLS;
  __shared__ short lin[6 * COLS * CIPAD];
  const int tid = threadIdx.x;
  const int hoblk = blockIdx.x % (HOUT / 2);
  const int b = blockIdx.x / (HOUT / 2);
  for (int i = tid; i < NE; i += 256) {
    const int r = i / (CIN * COLS);
    const int rem = i % (CIN * COLS);
    const int ci = rem / COLS;
    const int c = rem % COLS;
    const int hi = 4 * hoblk - 1 + r;
    const int wc = c - 1;
    float v = 0.f;
    if (hi >= 0 && hi < HIN && wc >= 0 && wc < HIN)
      v = in[((size_t)(b * CIN + ci) * HIN + hi) * HIN + wc];
    lin[(r * COLS + c) * CIPAD + ci] = f2bs(v);
  }
  __syncthreads();
  const int wq = __builtin_amdgcn_readfirstlane(tid >> 6);
  const int lane = tid & 63;
  const int l15 = lane & 15;
  const int quad = lane >> 4;
  const int mtile = wq % MT;
  const int cobase = (wq / MT) * (NT * 16);
  const int p = mtile * 16 + l15;
  const int dr = p / HOUT;
  const int col = p % HOUT;
  f32x4 acc[NT];
#pragma unroll
  for (int n = 0; n < NT; ++n) acc[n] = (f32x4){0.f, 0.f, 0.f, 0.f};
  const short* wrow = wT + (size_t)(cobase + l15) * CIN + quad * 8;
  for (int ky = 0; ky < 4; ++ky) {
    for (int kx = 0; kx < 4; ++kx) {
      const short* arow = &lin[((2 * dr + ky) * COLS + 2 * col + kx) * CIPAD + quad * 8];
      const short* wt = wrow + (size_t)(ky * 4 + kx) * COUT * CIN;
#pragma unroll
      for (int kk = 0; kk < KK; ++kk) {
        bf16x8 a = *(const bf16x8*)(arow + kk * 32);
#pragma unroll
        for (int n = 0; n < NT; ++n) {
          bf16x8 bf = *(const bf16x8*)(wt + n * 16 * CIN + kk * 32);
          acc[n] = __builtin_amdgcn_mfma_f32_16x16x32_bf16(a, bf, acc[n], 0, 0, 0);
        }
      }
    }
  }
#pragma unroll
  for (int n = 0; n < NT; ++n) {
    const int co = cobase + n * 16 + l15;
    const float bv = bias[co];
#pragma unroll
    for (int r = 0; r < 4; ++r) {
      const int pp = mtile * 16 + quad * 4 + r;
      const int dr2 = pp / HOUT;
      const int c2 = pp % HOUT;
      const int ho = hoblk * 2 + dr2;
      float v = acc[n][r] + bv;
      v = v > 0.f ? v : 0.f;
      if (OUTMODE == 0) {
        out[((size_t)(b * COUT + co) * HOUT + ho) * HOUT + c2] = v;
      } else {
        const size_t o = ((size_t)b * 64 + ho * 8 + c2) * COUT + co;
        out[o] = v;
        out2[o] = v;
        outbf[o] = f2bs(v);
      }
    }
  }
}

// ---------------- 3x3 s1 p1 conv on 8x8 via MFMA, pm-bf16 in, pm-f32 out + stats ----------------
// Block: (b, co-quarter 32). grid = 64*4.
__global__ __launch_bounds__(256) void k_resmfma(const short* __restrict__ hpm,
                                                 const short* __restrict__ wT,
                                                 float* __restrict__ outpm,
                                                 float* __restrict__ stats) {
  constexpr int CIPAD = 136;  // shorts; stride 68 words = 4 mod 32 banks
  __shared__ short lin[100 * CIPAD];
  const int tid = threadIdx.x;
  const int b = blockIdx.x >> 2;
  const int cobase = (blockIdx.x & 3) * 32;
  const short* hb = hpm + ((size_t)b << 13);
  for (int i = tid; i < 1600; i += 256) {  // 100 pixels x 16 bf16x8-chunks
    const int pixel = i >> 4, ch = i & 15;
    const int r = pixel / 10, c = pixel % 10;
    bf16x8 v = (bf16x8)(short)0;
    if (r >= 1 && r <= 8 && c >= 1 && c <= 8)
      v = *(const bf16x8*)(hb + (((r - 1) << 3) + (c - 1)) * 128 + ch * 8);
    *(bf16x8*)(&lin[pixel * CIPAD + ch * 8]) = v;
  }
  __syncthreads();
  const int wq = __builtin_amdgcn_readfirstlane(tid >> 6);
  const int lane = tid & 63;
  const int l15 = lane & 15, quad = lane >> 4;
  const int p = wq * 16 + l15;
  const int py = p >> 3, px = p & 7;
  f32x4 acc[2];
  acc[0] = (f32x4){0.f, 0.f, 0.f, 0.f};
  acc[1] = (f32x4){0.f, 0.f, 0.f, 0.f};
  const short* wrow = wT + (size_t)(cobase + l15) * 128 + quad * 8;
  for (int t = 0; t < 9; ++t) {
    const int ky = t / 3, kx = t % 3;
    const short* arow = &lin[((py + ky) * 10 + px + kx) * CIPAD + quad * 8];
    const short* wt = wrow + (size_t)t * 16384;
#pragma unroll
    for (int kk = 0; kk < 4; ++kk) {
      bf16x8 a = *(const bf16x8*)(arow + kk * 32);
#pragma unroll
      for (int n = 0; n < 2; ++n) {
        bf16x8 bf = *(const bf16x8*)(wt + n * 16 * 128 + kk * 32);
        acc[n] = __builtin_amdgcn_mfma_f32_16x16x32_bf16(a, bf, acc[n], 0, 0, 0);
      }
    }
  }
  float* ob = outpm + ((size_t)b << 13);
#pragma unroll
  for (int n = 0; n < 2; ++n) {
    const int co = cobase + n * 16 + l15;
    float s = 0.f, q = 0.f;
#pragma unroll
    for (int r = 0; r < 4; ++r) {
      const float v = acc[n][r];
      ob[(size_t)(wq * 16 + quad * 4 + r) * 128 + co] = v;
      s += v;
      q += v * v;
    }
    s += __shfl_down(s, 32); q += __shfl_down(q, 32);
    s += __shfl_down(s, 16); q += __shfl_down(q, 16);
    if (lane < 16) {
      atomicAdd(&stats[co], s);
      atomicAdd(&stats[128 + co], q);
    }
  }
}

// ---------------- BN + relu (pixel-major) -> bf16 pm ----------------
__global__ __launch_bounds__(256) void k_bnrelu(const float* __restrict__ inpm,
                                                const float* __restrict__ stats,
                                                const float* __restrict__ g,
                                                const float* __restrict__ bb,
                                                short* __restrict__ outbf) {
  const int idx = blockIdx.x * 256 + threadIdx.x;  // 524288, co fastest
  const int co = idx & 127;
  const float mu = stats[co] * (1.f / 4096.f);
  const float var = stats[128 + co] * (1.f / 4096.f) - mu * mu;
  const float v = g[co] * (inpm[idx] - mu) * rsqrtf(var + 1e-5f) + bb[co];
  outbf[idx] = f2bs(v > 0.f ? v : 0.f);
}

// ---------------- BN + residual + relu + map_skip accumulate (pixel-major) ----------------
__global__ __launch_bounds__(256) void k_bnadd(const float* __restrict__ inpm,
                                               const float* __restrict__ stats,
                                               const float* __restrict__ g,
                                               const float* __restrict__ bb,
                                               const float* __restrict__ identpm,
                                               float* __restrict__ houtpm,
                                               short* __restrict__ houtbf,
                                               float* __restrict__ mspm) {
  const int idx = blockIdx.x * 256 + threadIdx.x;
  const int co = idx & 127;
  const float mu = stats[co] * (1.f / 4096.f);
  const float var = stats[128 + co] * (1.f / 4096.f) - mu * mu;
  float v = g[co] * (inpm[idx] - mu) * rsqrtf(var + 1e-5f) + bb[co];
  v += identpm[idx];
  v = v > 0.f ? v : 0.f;
  houtpm[idx] = v;
  houtbf[idx] = f2bs(v);
  mspm[idx] += v;
}

// ---------------- map_skip transpose: pm [b][pix][co] -> canonical [b][co][pix] ----------------
__global__ __launch_bounds__(256) void k_mstrans(const float* __restrict__ mspm,
                                                 float* __restrict__ out0) {
  __shared__ float t[64 * 132];
  const int b = blockIdx.x;
  const int tid = threadIdx.x;
  const float* sp = mspm + ((size_t)b << 13);
  for (int i = tid; i < 8192; i += 256) {
    const int pix = i >> 7, co = i & 127;
    t[pix * 132 + co] = sp[i];
  }
  __syncthreads();
  float* dp = out0 + ((size_t)b << 13);
  for (int i = tid; i < 8192; i += 256) {
    const int co = i >> 6, pix = i & 63;
    dp[i] = t[pix * 132 + co];
  }
}

// ---------------- FC via MFMA: [64,8192]bf16 x [256,8192]bf16^T, k-split partials ----------------
// grid = 4 nblk x 32 kblk; block = 4 waves, wave = 16-co n-tile x 4 m-tiles (m=b).
__global__ __launch_bounds__(256) void k_fcmfma(const short* __restrict__ hbf,
                                                const short* __restrict__ wbf,
                                                float* __restrict__ part) {
  const int nb = blockIdx.x & 3;
  const int kb = blockIdx.x >> 2;  // 0..31, chunk of 256 k
  const int wq = __builtin_amdgcn_readfirstlane((int)(threadIdx.x >> 6));
  const int lane = threadIdx.x & 63;
  const int l15 = lane & 15, quad = lane >> 4;
  const int k0 = kb * 256 + quad * 8;
  const short* wp = wbf + (size_t)(nb * 64 + wq * 16 + l15) * 8192 + k0;
  const short* hp = hbf + (size_t)l15 * 8192 + k0;
  f32x4 acc[4];
#pragma unroll
  for (int m = 0; m < 4; ++m) acc[m] = (f32x4){0.f, 0.f, 0.f, 0.f};
  for (int ks = 0; ks < 8; ++ks) {
    bf16x8 bfr = *(const bf16x8*)(wp + ks * 32);
#pragma unroll
    for (int m = 0; m < 4; ++m) {
      bf16x8 a = *(const bf16x8*)(hp + (size_t)m * 16 * 8192 + ks * 32);
      acc[m] = __builtin_amdgcn_mfma_f32_16x16x32_bf16(a, bfr, acc[m], 0, 0, 0);
    }
  }
#pragma unroll
  for (int m = 0; m < 4; ++m)
#pragma unroll
    for (int r = 0; r < 4; ++r) {
      const int b = m * 16 + quad * 4 + r;
      part[((size_t)kb * 64 + b) * 256 + nb * 64 + wq * 16 + l15] = acc[m][r];
    }
}

__global__ __launch_bounds__(256) void k_fcred(const float* __restrict__ part,
                                               const float* __restrict__ bias,
                                               float* __restrict__ out1) {
  const int idx = blockIdx.x * 256 + threadIdx.x;  // 16384
  const int j = idx & 255;
  float s = 0.f;
#pragma unroll 8
  for (int kb = 0; kb < 32; ++kb) s += part[(size_t)kb * 16384 + idx];
  const float v = s + bias[j];
  out1[idx] = v > 0.f ? v : 0.f;
}

extern "C" void kernel_launch(void* const* d_in, const int* in_sizes, int n_in,
                              void* d_out, int out_size, void* d_ws, size_t ws_size,
                              hipStream_t stream) {
  const float* xin = (const float*)d_in[0];
  const float* emb = (const float*)d_in[1];
  const int* xy = (const int*)d_in[2];
  const float* c1w = (const float*)d_in[3];
  const float* pw = (const float*)d_in[4];
  const float* pb = (const float*)d_in[5];
  const float* d1w = (const float*)d_in[6];
  const float* d1b = (const float*)d_in[7];
  const float* d2w = (const float*)d_in[8];
  const float* d2b = (const float*)d_in[9];
  const float* d3w = (const float*)d_in[10];
  const float* d3b = (const float*)d_in[11];
  const float* rc1w = (const float*)d_in[12];
  const float* rbn1g = (const float*)d_in[13];
  const float* rbn1b = (const float*)d_in[14];
  const float* rc2w = (const float*)d_in[15];
  const float* rbn2g = (const float*)d_in[16];
  const float* rbn2b = (const float*)d_in[17];
  const float* fcw = (const float*)d_in[18];
  const float* fcb = (const float*)d_in[19];

  float* out0 = (float*)d_out;   // map_skip [64,128,8,8] f32
  float* out1 = out0 + 524288;   // embedded_spatial [64,256] f32

  float* F = (float*)d_ws;
  float* scat = F + 0;           // [0, 8388608)
  float* h0 = F + 8388608;       // dead after ds1; region reused below
  float* h1 = F + 0;             // reuses scat (dead after ds2); later fcpart reuses too
  float* h2 = F + 4194304;
  float* hApm = F + 6291456;     // 524288 pm f32
  float* hBpm = F + 6815744;     // 524288 pm f32
  float* tmppm = F + 7340032;    // 524288 pm f32 (pre-BN)
  float* mspm = F + 7864320;     // 524288 pm f32 map_skip accum; ends 8388608
  // h0-region reuse (valid after ds1):
  float* stats = F + 8388608;                  // 2048 f
  short* pmbfA = (short*)(F + 8390656);        // 524288 shorts (262144 f)
  short* pmbfB = (short*)(F + 8652800);
  short* obufbf = (short*)(F + 8914944);
  short* wfcbf = (short*)(F + 9177088);        // 2097152 shorts (1048576 f) -> ends 10225664
  float* fcpart = F + 0;                       // 32*64*256 = 524288 f (after ds2, scat/h1 dead)
  // persistent weight region:
  short* wTr1 = (short*)(F + 16777216);        // 589824
  short* wTr2 = wTr1 + 589824;
  short* wTds1 = wTr2 + 589824;                // 32768
  short* wTds2 = wTds1 + 32768;                // 131072
  short* wTds3 = wTds2 + 131072;               // 262144; ends F+17580032 (70.3 MB)

  hipMemsetAsync(scat, 0, 8388608 * sizeof(float), stream);
  k_wtres<<<2304, 256, 0, stream>>>(rc1w, wTr1);
  k_wtres<<<2304, 256, 0, stream>>>(rc2w, wTr2);
  k_wtds<32, 64><<<128, 256, 0, stream>>>(d1w, wTds1);
  k_wtds<64, 128><<<512, 256, 0, stream>>>(d2w, wTds2);
  k_wtds<128, 128><<<1024, 256, 0, stream>>>(d3w, wTds3);

  k_scatter<<<1024, 256, 0, stream>>>(emb, xy, c1w, scat);
  k_proj2<<<2048, 256, 0, stream>>>(scat, xin, pw, pb, h0);
  // ds1: grid = 64 b * 16 ho-blocks; MT=4, NT=4
  k_dsmfma<32, 64, 64, 48, 4, 4, 0><<<1024, 256, 0, stream>>>(h0, wTds1, d1b, h1, h1, pmbfA);
  // h0 dead: set up reused region
  hipMemsetAsync(stats, 0, 2048 * sizeof(float), stream);
  k_wfc<<<256, 256, 0, stream>>>(fcw, wfcbf);
  // ds2: grid = 64 * 8; MT=2, NT=4
  k_dsmfma<64, 128, 32, 80, 2, 4, 0><<<512, 256, 0, stream>>>(h1, wTds2, d2b, h2, h2, pmbfA);
  // ds3: grid = 64 * 4; MT=1, NT=2; pm triple-store (h_pm, ms_pm seed, h_pm bf16)
  k_dsmfma<128, 128, 16, 144, 1, 2, 1><<<256, 256, 0, stream>>>(h2, wTds3, d3b, hApm, mspm, pmbfA);

  float* cur = hApm;  float* nxt = hBpm;
  short* curbf = pmbfA; short* nxtbf = pmbfB;
  for (int i = 0; i < 4; ++i) {
    float* sA = stats + i * 512;
    float* sB = stats + i * 512 + 256;
    k_resmfma<<<256, 256, 0, stream>>>(curbf, wTr1 + (size_t)i * 147456, tmppm, sA);
    k_bnrelu<<<2048, 256, 0, stream>>>(tmppm, sA, rbn1g + i * 128, rbn1b + i * 128, obufbf);
    k_resmfma<<<256, 256, 0, stream>>>(obufbf, wTr2 + (size_t)i * 147456, tmppm, sB);
    k_bnadd<<<2048, 256, 0, stream>>>(tmppm, sB, rbn2g + i * 128, rbn2b + i * 128, cur, nxt,
                                      nxtbf, mspm);
    float* sw = cur; cur = nxt; nxt = sw;
    short* swb = curbf; curbf = nxtbf; nxtbf = swb;
  }
  k_mstrans<<<64, 256, 0, stream>>>(mspm, out0);
  k_fcmfma<<<128, 256, 0, stream>>>(curbf, wfcbf, fcpart);
  k_fcred<<<64, 256, 0, stream>>>(fcpart, fcb, out1);
}

// Round 7
// 437.879 us; speedup vs baseline: 9.5168x; 1.1789x over previous
//
#include <hip/hip_runtime.h>
#include <hip/hip_bf16.h>

typedef __attribute__((ext_vector_type(8))) short bf16x8;  // 8 bf16 (4 VGPRs)
typedef __attribute__((ext_vector_type(4))) short bf16x4;
typedef __attribute__((ext_vector_type(4))) float f32x4;   // MFMA C/D frag

__device__ __forceinline__ short f2bs(float v) {
  __hip_bfloat16 h = __float2bfloat16(v);
  return *reinterpret_cast<short*>(&h);
}

// ---------- weight transforms: [co][ci][kh][kw] f32 -> [tap][co][ci] bf16 ----------
__global__ __launch_bounds__(256) void k_wtres(const float* __restrict__ src,
                                               short* __restrict__ dst) {
  const int i = blockIdx.x * 256 + threadIdx.x;  // 4 layers * 9 * 128 * 128
  if (i >= 589824) return;
  const int layer = i / 147456;
  const int rem = i % 147456;
  const int tap = rem / 16384;
  const int r2 = rem & 16383;
  const int co = r2 >> 7, ci = r2 & 127;
  dst[i] = f2bs(src[(((size_t)layer * 16384 + co * 128 + ci) * 9) + tap]);
}

template <int CIN, int COUT>
__global__ __launch_bounds__(256) void k_wtds(const float* __restrict__ src,
                                              short* __restrict__ dst) {
  const int i = blockIdx.x * 256 + threadIdx.x;  // 16 * COUT * CIN
  if (i >= 16 * COUT * CIN) return;
  const int tap = i / (COUT * CIN);
  const int rem = i % (COUT * CIN);
  const int co = rem / CIN, ci = rem % CIN;
  dst[i] = f2bs(src[((size_t)(co * CIN + ci)) * 16 + tap]);
}

// ---------- fc weight: [j][co*64+pix] f32 -> [j][pix*128+co] bf16 (block per j) ----------
__global__ __launch_bounds__(256) void k_wfc(const float* __restrict__ src,
                                             short* __restrict__ dst) {
  __shared__ float ld[128 * 65];
  const int j = blockIdx.x;
  const int tid = threadIdx.x;
  const float* sp = src + (size_t)j * 8192;
  for (int i = tid; i < 8192; i += 256) {
    const int co = i >> 6, pix = i & 63;
    ld[co * 65 + pix] = sp[i];
  }
  __syncthreads();
  short* dp = dst + (size_t)j * 8192;
  for (int i = tid; i < 8192; i += 256) {
    const int pix = i >> 7, co = i & 127;
    dp[i] = f2bs(ld[co * 65 + pix]);
  }
}

// ---------------- scatter: entity GEMM + relu + scatter-add ----------------
__global__ __launch_bounds__(256) void k_scatter(const float* __restrict__ emb,
                                                 const int* __restrict__ xy,
                                                 const float* __restrict__ w,
                                                 float* __restrict__ scat) {
  __shared__ float wl[32 * 257];
  __shared__ float el[32 * 256];
  const int tid = threadIdx.x;
  for (int i = tid; i < 32 * 256; i += 256) {
    int c = i >> 8, d = i & 255;
    wl[c * 257 + d] = w[i];
  }
  const int g0 = blockIdx.x * 32;
  for (int i = tid; i < 8192; i += 256) el[i] = emb[(size_t)g0 * 256 + i];
  __syncthreads();
  const int e0 = tid >> 5, c = tid & 31;
  const float* wr = &wl[c * 257];
#pragma unroll
  for (int t = 0; t < 4; ++t) {
    const int e = e0 + t * 8;
    const int g = g0 + e;
    const float* er = &el[e << 8];
    float acc = 0.f;
#pragma unroll 16
    for (int d = 0; d < 256; ++d) acc += er[d] * wr[d];
    const int* bp = xy + (size_t)g * 16;
    int xv = 0, yv = 0;
#pragma unroll
    for (int j = 0; j < 8; ++j) xv = (xv << 1) | bp[j];
#pragma unroll
    for (int j = 8; j < 16; ++j) yv = (yv << 1) | bp[j];
    const bool valid = (bp[0] != -1000000000);
    float v = acc > 0.f ? acc : 0.f;
    if (valid && v != 0.f) {
      const int b = g >> 9;
      atomicAdd(&scat[(((size_t)b * 32 + c) << 12) + ((yv >> 2) << 6) + (xv >> 2)], v);
    }
  }
}

// ---------------- project: concat + 1x1 conv + relu -> pixel-major bf16 ----------------
// block = (b, 128-pixel tile); thread = 4 pix x 4 co; stores 8B (4 co) contiguous pm bf16
__global__ __launch_bounds__(256) void k_proj2(const float* __restrict__ scat,
                                               const float* __restrict__ xin,
                                               const float* __restrict__ pw,
                                               const float* __restrict__ pb,
                                               short* __restrict__ h0pm) {
  __shared__ float sl[50 * 128];
  __shared__ float wlds[50 * 32];
  const int tid = threadIdx.x;
  const int b = blockIdx.x >> 5;
  const int yx0 = (blockIdx.x & 31) << 7;
  for (int i = tid; i < 1600; i += 256) {
    const int co = i / 50, ci = i % 50;
    wlds[ci * 32 + co] = pw[i];
  }
  for (int i = tid; i < 6400; i += 256) {
    const int ci = i >> 7, p = i & 127;
    sl[i] = (ci < 32) ? scat[((size_t)(b * 32 + ci) << 12) + yx0 + p]
                      : xin[(size_t)(b * 18 + ci - 32) * 4096 + yx0 + p];
  }
  __syncthreads();
  const int cog = tid & 7, pg = tid >> 3;  // co0 = cog*4, pix0 = pg*4
  const int co0 = cog << 2, pix0 = pg << 2;
  float acc[4][4];
#pragma unroll
  for (int n = 0; n < 4; ++n)
#pragma unroll
    for (int m = 0; m < 4; ++m) acc[n][m] = pb[co0 + n];
  for (int ci = 0; ci < 50; ++ci) {
    const float4 a = *(const float4*)&sl[(ci << 7) + pix0];
    const float4 wv = *(const float4*)&wlds[ci * 32 + co0];
    const float am[4] = {a.x, a.y, a.z, a.w};
    const float wn[4] = {wv.x, wv.y, wv.z, wv.w};
#pragma unroll
    for (int n = 0; n < 4; ++n)
#pragma unroll
      for (int m = 0; m < 4; ++m) acc[n][m] += wn[n] * am[m];
  }
#pragma unroll
  for (int m = 0; m < 4; ++m) {
    bf16x4 o;
#pragma unroll
    for (int n = 0; n < 4; ++n) {
      const float v = acc[n][m];
      o[n] = f2bs(v > 0.f ? v : 0.f);
    }
    *(bf16x4*)(h0pm + ((size_t)b * 4096 + yx0 + pix0 + m) * 32 + co0) = o;
  }
}

// ---------------- 4x4 s2 p1 conv + bias + relu via MFMA, pm bf16 in/out ----------------
// Block: (b, ROWSO output rows, co-split). LDS halo [2*ROWSO+2][HIN+2][CIPAD] bf16
// staged with 16B vector copies. OUTMODE 1 (ds3): triple store (pm bf16, pm f32, ms seed).
template <int CIN, int COUT, int HIN, int ROWSO, int COSPLIT, int MT, int NT, int OUTMODE>
__global__ __launch_bounds__(256) void k_ds2(const short* __restrict__ inpm,
                                             const short* __restrict__ wT,
                                             const float* __restrict__ bias,
                                             short* __restrict__ outbf,
                                             float* __restrict__ outf,
                                             float* __restrict__ msf) {
  constexpr int HOUT = HIN / 2;
  constexpr int ROWS = 2 * ROWSO + 2;
  constexpr int COLS = HIN + 2;
  constexpr int CHUNKS = CIN / 8;
  constexpr int KK = CIN / 32;
  constexpr int CIPAD = CIN + 8;
  constexpr int NHO = HOUT / ROWSO;
  __shared__ short lin[ROWS * COLS * CIPAD];
  const int tid = threadIdx.x;
  int bx = blockIdx.x;
  const int co_blk = (COSPLIT > 1) ? (bx % COSPLIT) : 0;
  if (COSPLIT > 1) bx /= COSPLIT;
  const int hoblk = bx % NHO;
  const int b = bx / NHO;
  for (int i = tid; i < ROWS * COLS * CHUNKS; i += 256) {
    const int ch = i % CHUNKS;
    const int pixv = i / CHUNKS;
    const int r = pixv / COLS, c = pixv % COLS;
    const int hi = 2 * ROWSO * hoblk - 1 + r;
    const int wc = c - 1;
    bf16x8 v = (bf16x8)(short)0;
    if (hi >= 0 && hi < HIN && wc >= 0 && wc < HIN)
      v = *(const bf16x8*)(inpm + ((size_t)(b * HIN + hi) * HIN + wc) * CIN + ch * 8);
    *(bf16x8*)(&lin[(r * COLS + c) * CIPAD + ch * 8]) = v;
  }
  __syncthreads();
  const int wq = __builtin_amdgcn_readfirstlane(tid >> 6);
  const int lane = tid & 63;
  const int l15 = lane & 15, quad = lane >> 4;
  const int mtile = (MT > 1) ? (wq % MT) : 0;
  const int cogrp = wq / MT;
  const int cobase = co_blk * (COUT / COSPLIT) + cogrp * (NT * 16);
  const int p = mtile * 16 + l15;
  const int dr = p / HOUT;
  const int col = p % HOUT;
  f32x4 acc[NT];
#pragma unroll
  for (int n = 0; n < NT; ++n) acc[n] = (f32x4){0.f, 0.f, 0.f, 0.f};
  const short* wrow = wT + (size_t)(cobase + l15) * CIN + quad * 8;
  for (int ky = 0; ky < 4; ++ky) {
    for (int kx = 0; kx < 4; ++kx) {
      const short* arow = &lin[((2 * dr + ky) * COLS + 2 * col + kx) * CIPAD + quad * 8];
      const short* wt = wrow + (size_t)(ky * 4 + kx) * COUT * CIN;
#pragma unroll
      for (int kk = 0; kk < KK; ++kk) {
        bf16x8 a = *(const bf16x8*)(arow + kk * 32);
#pragma unroll
        for (int n = 0; n < NT; ++n) {
          bf16x8 bf = *(const bf16x8*)(wt + n * 16 * CIN + kk * 32);
          acc[n] = __builtin_amdgcn_mfma_f32_16x16x32_bf16(a, bf, acc[n], 0, 0, 0);
        }
      }
    }
  }
#pragma unroll
  for (int n = 0; n < NT; ++n) {
    const int co = cobase + n * 16 + l15;
    const float bv = bias[co];
#pragma unroll
    for (int r = 0; r < 4; ++r) {
      const int pp = mtile * 16 + quad * 4 + r;
      const int dr2 = pp / HOUT;
      const int c2 = pp % HOUT;
      const int ho = hoblk * ROWSO + dr2;
      float v = acc[n][r] + bv;
      v = v > 0.f ? v : 0.f;
      const size_t o = ((size_t)b * HOUT * HOUT + ho * HOUT + c2) * COUT + co;
      outbf[o] = f2bs(v);
      if (OUTMODE == 1) {
        outf[o] = v;
        msf[o] = v;
      }
    }
  }
}

// ---------------- 3x3 s1 p1 conv on 8x8 via MFMA, fused stats ----------------
// grid = 64 b x 8 co-groups (16 co). BNIN=0: input pm bf16. BNIN=1: input pm f32,
// apply BN(statsIn)+relu during staging (replaces separate bnrelu kernel).
template <int BNIN>
__global__ __launch_bounds__(256) void k_resmfma(const short* __restrict__ hbfin,
                                                 const float* __restrict__ fin,
                                                 const float* __restrict__ statsIn,
                                                 const float* __restrict__ gIn,
                                                 const float* __restrict__ bIn,
                                                 const short* __restrict__ wT,
                                                 float* __restrict__ outpm,
                                                 float* __restrict__ statsOut) {
  constexpr int CIPAD = 136;
  __shared__ short lin[100 * CIPAD];
  __shared__ float bnsc[128], bnsh[128];
  const int tid = threadIdx.x;
  const int b = blockIdx.x >> 3;
  const int cobase = (blockIdx.x & 7) << 4;
  if (BNIN == 1) {
    if (tid < 128) {
      const float mu = statsIn[tid] * (1.f / 4096.f);
      const float var = statsIn[128 + tid] * (1.f / 4096.f) - mu * mu;
      const float sc = gIn[tid] * rsqrtf(var + 1e-5f);
      bnsc[tid] = sc;
      bnsh[tid] = bIn[tid] - mu * sc;
    }
    __syncthreads();
  }
  if (BNIN == 0) {
    const short* hb = hbfin + ((size_t)b << 13);
    for (int i = tid; i < 1600; i += 256) {
      const int pixel = i >> 4, ch = i & 15;
      const int r = pixel / 10, c = pixel % 10;
      bf16x8 v = (bf16x8)(short)0;
      if (r >= 1 && r <= 8 && c >= 1 && c <= 8)
        v = *(const bf16x8*)(hb + (((r - 1) << 3) + (c - 1)) * 128 + ch * 8);
      *(bf16x8*)(&lin[pixel * CIPAD + ch * 8]) = v;
    }
  } else {
    const float* fb = fin + ((size_t)b << 13);
    for (int i = tid; i < 3200; i += 256) {  // 100 pixels x 32 float4-chunks
      const int pixel = i >> 5, c4 = i & 31;
      const int r = pixel / 10, c = pixel % 10;
      bf16x4 o = (bf16x4)(short)0;
      if (r >= 1 && r <= 8 && c >= 1 && c <= 8) {
        const float4 x = *(const float4*)(fb + (size_t)(((r - 1) << 3) + (c - 1)) * 128 + c4 * 4);
        const float xv[4] = {x.x, x.y, x.z, x.w};
#pragma unroll
        for (int k = 0; k < 4; ++k) {
          const int ci = c4 * 4 + k;
          const float v = xv[k] * bnsc[ci] + bnsh[ci];
          o[k] = f2bs(v > 0.f ? v : 0.f);
        }
      }
      *(bf16x4*)(&lin[pixel * CIPAD + c4 * 4]) = o;
    }
  }
  __syncthreads();
  const int wq = __builtin_amdgcn_readfirstlane(tid >> 6);
  const int lane = tid & 63;
  const int l15 = lane & 15, quad = lane >> 4;
  const int p = wq * 16 + l15;
  const int py = p >> 3, px = p & 7;
  f32x4 acc = (f32x4){0.f, 0.f, 0.f, 0.f};
  const short* wrow = wT + (size_t)(cobase + l15) * 128 + quad * 8;
  for (int t = 0; t < 9; ++t) {
    const int ky = t / 3, kx = t % 3;
    const short* arow = &lin[((py + ky) * 10 + px + kx) * CIPAD + quad * 8];
    const short* wt = wrow + (size_t)t * 16384;
#pragma unroll
    for (int kk = 0; kk < 4; ++kk) {
      bf16x8 a = *(const bf16x8*)(arow + kk * 32);
      bf16x8 bf = *(const bf16x8*)(wt + kk * 32);
      acc = __builtin_amdgcn_mfma_f32_16x16x32_bf16(a, bf, acc, 0, 0, 0);
    }
  }
  float* ob = outpm + ((size_t)b << 13);
  const int co = cobase + l15;
  float s = 0.f, q = 0.f;
#pragma unroll
  for (int r = 0; r < 4; ++r) {
    const float v = acc[r];
    ob[(size_t)(wq * 16 + quad * 4 + r) * 128 + co] = v;
    s += v;
    q += v * v;
  }
  s += __shfl_down(s, 32); q += __shfl_down(q, 32);
  s += __shfl_down(s, 16); q += __shfl_down(q, 16);
  if (lane < 16) {
    atomicAdd(&statsOut[co], s);
    atomicAdd(&statsOut[128 + co], q);
  }
}

// ---------------- BN + residual + relu + map_skip accumulate (pixel-major) ----------------
__global__ __launch_bounds__(256) void k_bnadd(const float* __restrict__ inpm,
                                               const float* __restrict__ stats,
                                               const float* __restrict__ g,
                                               const float* __restrict__ bb,
                                               const float* __restrict__ identpm,
                                               float* __restrict__ houtpm,
                                               short* __restrict__ houtbf,
                                               float* __restrict__ mspm) {
  const int idx = blockIdx.x * 256 + threadIdx.x;
  const int co = idx & 127;
  const float mu = stats[co] * (1.f / 4096.f);
  const float var = stats[128 + co] * (1.f / 4096.f) - mu * mu;
  float v = g[co] * (inpm[idx] - mu) * rsqrtf(var + 1e-5f) + bb[co];
  v += identpm[idx];
  v = v > 0.f ? v : 0.f;
  houtpm[idx] = v;
  houtbf[idx] = f2bs(v);
  mspm[idx] += v;
}

// ---------------- map_skip transpose: pm [b][pix][co] -> canonical [b][co][pix] ----------------
__global__ __launch_bounds__(256) void k_mstrans(const float* __restrict__ mspm,
                                                 float* __restrict__ out0) {
  __shared__ float t[64 * 132];
  const int b = blockIdx.x;
  const int tid = threadIdx.x;
  const float* sp = mspm + ((size_t)b << 13);
  for (int i = tid; i < 8192; i += 256) {
    const int pix = i >> 7, co = i & 127;
    t[pix * 132 + co] = sp[i];
  }
  __syncthreads();
  float* dp = out0 + ((size_t)b << 13);
  for (int i = tid; i < 8192; i += 256) {
    const int co = i >> 6, pix = i & 63;
    dp[i] = t[pix * 132 + co];
  }
}

// ---------------- FC via MFMA: k-split partials ----------------
__global__ __launch_bounds__(256) void k_fcmfma(const short* __restrict__ hbf,
                                                const short* __restrict__ wbf,
                                                float* __restrict__ part) {
  const int nb = blockIdx.x & 3;
  const int kb = blockIdx.x >> 2;
  const int wq = __builtin_amdgcn_readfirstlane((int)(threadIdx.x >> 6));
  const int lane = threadIdx.x & 63;
  const int l15 = lane & 15, quad = lane >> 4;
  const int k0 = kb * 256 + quad * 8;
  const short* wp = wbf + (size_t)(nb * 64 + wq * 16 + l15) * 8192 + k0;
  const short* hp = hbf + (size_t)l15 * 8192 + k0;
  f32x4 acc[4];
#pragma unroll
  for (int m = 0; m < 4; ++m) acc[m] = (f32x4){0.f, 0.f, 0.f, 0.f};
  for (int ks = 0; ks < 8; ++ks) {
    bf16x8 bfr = *(const bf16x8*)(wp + ks * 32);
#pragma unroll
    for (int m = 0; m < 4; ++m) {
      bf16x8 a = *(const bf16x8*)(hp + (size_t)m * 16 * 8192 + ks * 32);
      acc[m] = __builtin_amdgcn_mfma_f32_16x16x32_bf16(a, bfr, acc[m], 0, 0, 0);
    }
  }
#pragma unroll
  for (int m = 0; m < 4; ++m)
#pragma unroll
    for (int r = 0; r < 4; ++r) {
      const int b = m * 16 + quad * 4 + r;
      part[((size_t)kb * 64 + b) * 256 + nb * 64 + wq * 16 + l15] = acc[m][r];
    }
}

__global__ __launch_bounds__(256) void k_fcred(const float* __restrict__ part,
                                               const float* __restrict__ bias,
                                               float* __restrict__ out1) {
  const int idx = blockIdx.x * 256 + threadIdx.x;
  const int j = idx & 255;
  float s = 0.f;
#pragma unroll 8
  for (int kb = 0; kb < 32; ++kb) s += part[(size_t)kb * 16384 + idx];
  const float v = s + bias[j];
  out1[idx] = v > 0.f ? v : 0.f;
}

extern "C" void kernel_launch(void* const* d_in, const int* in_sizes, int n_in,
                              void* d_out, int out_size, void* d_ws, size_t ws_size,
                              hipStream_t stream) {
  const float* xin = (const float*)d_in[0];
  const float* emb = (const float*)d_in[1];
  const int* xy = (const int*)d_in[2];
  const float* c1w = (const float*)d_in[3];
  const float* pw = (const float*)d_in[4];
  const float* pb = (const float*)d_in[5];
  const float* d1w = (const float*)d_in[6];
  const float* d1b = (const float*)d_in[7];
  const float* d2w = (const float*)d_in[8];
  const float* d2b = (const float*)d_in[9];
  const float* d3w = (const float*)d_in[10];
  const float* d3b = (const float*)d_in[11];
  const float* rc1w = (const float*)d_in[12];
  const float* rbn1g = (const float*)d_in[13];
  const float* rbn1b = (const float*)d_in[14];
  const float* rc2w = (const float*)d_in[15];
  const float* rbn2g = (const float*)d_in[16];
  const float* rbn2b = (const float*)d_in[17];
  const float* fcw = (const float*)d_in[18];
  const float* fcb = (const float*)d_in[19];

  float* out0 = (float*)d_out;   // map_skip [64,128,8,8] f32
  float* out1 = out0 + 524288;   // embedded_spatial [64,256] f32

  float* F = (float*)d_ws;       // max extent 57.7 MB (< 70.3 MB proven in r2)
  float* scat = F + 0;           // [0, 8388608) f32 — dead after proj2; region reused:
  float* h1pm_f = F + 0;         //   h1pm bf16 [64][1024][64]  (2097152 f32 span)
  float* h2pm_f = F + 2097152;   //   h2pm bf16 [64][256][128]  (1048576)
  float* hApm = F + 3145728;     //   524288
  float* hBpm = F + 3670016;     //   524288
  float* tmppm = F + 4194304;    //   524288 (conv1 out, pre-BN)
  float* tmp2pm = F + 4718592;   //   524288 (conv2 out, pre-BN)
  float* mspm = F + 5242880;     //   524288
  short* pmbfA = (short*)(F + 5767168);   // 524288 shorts
  short* pmbfB = (short*)(F + 6029312);
  float* stats = F + 6291456;    //   2048
  float* fcpart = F + 6293504;   //   524288 (ends 6817792 < 8388608)
  short* h0pm = (short*)(F + 8388608);    // [64][4096][32] bf16 (4194304 f32 span)
  short* wfcbf = (short*)(F + 12582912);  // 2097152 shorts (1048576 f32)
  short* wTr1 = (short*)(F + 13631488);   // 589824 shorts
  short* wTr2 = wTr1 + 589824;
  short* wTds1 = wTr2 + 589824;           // 32768
  short* wTds2 = wTds1 + 32768;           // 131072
  short* wTds3 = wTds2 + 131072;          // 262144 -> ends F+14434304

  hipMemsetAsync(scat, 0, 8388608 * sizeof(float), stream);
  k_wtres<<<2304, 256, 0, stream>>>(rc1w, wTr1);
  k_wtres<<<2304, 256, 0, stream>>>(rc2w, wTr2);
  k_wtds<32, 64><<<128, 256, 0, stream>>>(d1w, wTds1);
  k_wtds<64, 128><<<512, 256, 0, stream>>>(d2w, wTds2);
  k_wtds<128, 128><<<1024, 256, 0, stream>>>(d3w, wTds3);
  k_wfc<<<256, 256, 0, stream>>>(fcw, wfcbf);

  k_scatter<<<1024, 256, 0, stream>>>(emb, xy, c1w, scat);
  k_proj2<<<2048, 256, 0, stream>>>(scat, xin, pw, pb, h0pm);
  hipMemsetAsync(stats, 0, 2048 * sizeof(float), stream);  // scat region dead from here
  short* h1pm = (short*)h1pm_f;
  short* h2pm = (short*)h2pm_f;
  // ds1: 2 rows/block, grid 64*16 = 1024; MT4 NT4
  k_ds2<32, 64, 64, 2, 1, 4, 4, 0><<<1024, 256, 0, stream>>>(h0pm, wTds1, d1b, h1pm, hApm, mspm);
  // ds2: 1 row/block, grid 64*16 = 1024; MT1 NT2 (4 co-groups of 32)
  k_ds2<64, 128, 32, 1, 1, 1, 2, 0><<<1024, 256, 0, stream>>>(h1pm, wTds2, d2b, h2pm, hApm, mspm);
  // ds3: 2 rows/block, co-split 2, grid 64*4*2 = 512; MT1 NT1; triple store
  k_ds2<128, 128, 16, 2, 2, 1, 1, 1><<<512, 256, 0, stream>>>(h2pm, wTds3, d3b, pmbfA, hApm, mspm);

  float* cur = hApm;  float* nxt = hBpm;
  short* curbf = pmbfA; short* nxtbf = pmbfB;
  for (int i = 0; i < 4; ++i) {
    float* sA = stats + i * 512;
    float* sB = stats + i * 512 + 256;
    // conv1: h(bf16) -> tmppm + statsA
    k_resmfma<0><<<512, 256, 0, stream>>>(curbf, nullptr, nullptr, nullptr, nullptr,
                                          wTr1 + (size_t)i * 147456, tmppm, sA);
    // conv2: BN1(tmppm)+relu fused in staging -> tmp2pm + statsB
    k_resmfma<1><<<512, 256, 0, stream>>>(nullptr, tmppm, sA, rbn1g + i * 128, rbn1b + i * 128,
                                          wTr2 + (size_t)i * 147456, tmp2pm, sB);
    k_bnadd<<<2048, 256, 0, stream>>>(tmp2pm, sB, rbn2g + i * 128, rbn2b + i * 128, cur, nxt,
                                      nxtbf, mspm);
    float* sw = cur; cur = nxt; nxt = sw;
    short* swb = curbf; curbf = nxtbf; nxtbf = swb;
  }
  k_mstrans<<<64, 256, 0, stream>>>(mspm, out0);
  k_fcmfma<<<128, 256, 0, stream>>>(curbf, wfcbf, fcpart);
  k_fcred<<<64, 256, 0, stream>>>(fcpart, fcb, out1);
}

// Round 8
// 405.446 us; speedup vs baseline: 10.2781x; 1.0800x over previous
//
#include <hip/hip_runtime.h>
#include <hip/hip_bf16.h>

typedef __attribute__((ext_vector_type(8))) short bf16x8;  // 8 bf16 (4 VGPRs)
typedef __attribute__((ext_vector_type(4))) short bf16x4;
typedef __attribute__((ext_vector_type(4))) float f32x4;   // MFMA C/D frag

__device__ __forceinline__ short f2bs(float v) {
  __hip_bfloat16 h = __float2bfloat16(v);
  return *reinterpret_cast<short*>(&h);
}

// ================ fused weight transforms (one launch) ================
// grid layout: [0,2304) wtres rc1w | [2304,4608) wtres rc2w | [4608,4736) wtds1
// [4736,5248) wtds2 | [5248,6272) wtds3 | [6272,6528) wfc | [6528,6560) wsc | [6560,6568) wproj
__global__ __launch_bounds__(256) void k_wall(
    const float* __restrict__ rc1w, const float* __restrict__ rc2w,
    const float* __restrict__ d1w, const float* __restrict__ d2w,
    const float* __restrict__ d3w, const float* __restrict__ fcw,
    const float* __restrict__ c1w, const float* __restrict__ pw,
    short* __restrict__ wTr1, short* __restrict__ wTr2, short* __restrict__ wTds1,
    short* __restrict__ wTds2, short* __restrict__ wTds3, short* __restrict__ wfcbf,
    short* __restrict__ wsc, short* __restrict__ wproj) {
  __shared__ float ld[128 * 65];
  const int bx = blockIdx.x;
  const int tid = threadIdx.x;
  if (bx < 4608) {  // res-conv weights: [l][co][ci][3][3] -> [l][tap][co][ci]
    const float* src = (bx < 2304) ? rc1w : rc2w;
    short* dst = (bx < 2304) ? wTr1 : wTr2;
    const int i = (bx % 2304) * 256 + tid;
    if (i < 589824) {
      const int layer = i / 147456;
      const int rem = i % 147456;
      const int tap = rem / 16384;
      const int r2 = rem & 16383;
      const int co = r2 >> 7, ci = r2 & 127;
      dst[i] = f2bs(src[(((size_t)layer * 16384 + co * 128 + ci) * 9) + tap]);
    }
  } else if (bx < 6272) {  // ds weights: [co][ci][4][4] -> [tap][co][ci]
    int CIN, n, base;
    const float* src;
    short* dst;
    if (bx < 4736) { CIN = 32; n = 32768; base = 4608; src = d1w; dst = wTds1; }
    else if (bx < 5248) { CIN = 64; n = 131072; base = 4736; src = d2w; dst = wTds2; }
    else { CIN = 128; n = 262144; base = 5248; src = d3w; dst = wTds3; }
    const int i = (bx - base) * 256 + tid;
    if (i < n) {
      const int COCI = n / 16;
      const int tap = i / COCI;
      const int rem = i % COCI;
      dst[i] = f2bs(src[(size_t)rem * 16 + tap]);
    }
  } else if (bx < 6528) {  // fc: [j][co*64+pix] -> [j][pix*128+co]
    const int j = bx - 6272;
    const float* sp = fcw + (size_t)j * 8192;
    for (int i = tid; i < 8192; i += 256) {
      const int co = i >> 6, pix = i & 63;
      ld[co * 65 + pix] = sp[i];
    }
    __syncthreads();
    short* dp = wfcbf + (size_t)j * 8192;
    for (int i = tid; i < 8192; i += 256) {
      const int pix = i >> 7, co = i & 127;
      dp[i] = f2bs(ld[co * 65 + pix]);
    }
  } else if (bx < 6560) {  // scatter weight: [co][ci] f32 -> bf16 (same layout)
    const int i = (bx - 6528) * 256 + tid;
    if (i < 8192) wsc[i] = f2bs(c1w[i]);
  } else {  // project weight: [co][50] -> [co][64] zero-padded
    const int i = (bx - 6560) * 256 + tid;
    if (i < 2048) {
      const int co = i >> 6, k = i & 63;
      wproj[i] = (k < 50) ? f2bs(pw[co * 50 + k]) : (short)0;
    }
  }
}

// ================ scatter: entity GEMM (MFMA) + relu + coalesced scatter-add ================
// 64 entities/block (grid 512). scat_pm [b][yx][32] f32 pre-zeroed.
__global__ __launch_bounds__(256) void k_scatmfma(const float* __restrict__ emb,
                                                  const int* __restrict__ xy,
                                                  const short* __restrict__ wsc,
                                                  float* __restrict__ scat_pm) {
  constexpr int CIP = 264;  // shorts; 132 words = 4 mod 32 -> 2-way (free); 16B aligned
  __shared__ short abf[64 * CIP];
  __shared__ int flat[64];
  const int tid = threadIdx.x;
  const int e0 = blockIdx.x * 64;
  const float4* eg = (const float4*)(emb + (size_t)e0 * 256);
  for (int i = tid; i < 4096; i += 256) {
    const int e = i >> 6, k4 = i & 63;
    const float4 v = eg[(size_t)e * 64 + k4];
    bf16x4 o;
    o[0] = f2bs(v.x); o[1] = f2bs(v.y); o[2] = f2bs(v.z); o[3] = f2bs(v.w);
    *(bf16x4*)(&abf[e * CIP + k4 * 4]) = o;
  }
  if (tid < 64) {
    const int* bp = xy + (size_t)(e0 + tid) * 16;
    int xv = 0, yv = 0;
#pragma unroll
    for (int j = 0; j < 8; ++j) xv = (xv << 1) | bp[j];
#pragma unroll
    for (int j = 8; j < 16; ++j) yv = (yv << 1) | bp[j];
    flat[tid] = (bp[0] != -1000000000)
                    ? (((e0 + tid) >> 9) * 4096 + ((yv >> 2) << 6) + (xv >> 2))
                    : -1;
  }
  __syncthreads();
  const int wq = __builtin_amdgcn_readfirstlane(tid >> 6);
  const int lane = tid & 63;
  const int l15 = lane & 15, quad = lane >> 4;
  f32x4 acc[2];
  acc[0] = (f32x4){0.f, 0.f, 0.f, 0.f};
  acc[1] = (f32x4){0.f, 0.f, 0.f, 0.f};
  const short* arow = &abf[(wq * 16 + l15) * CIP + quad * 8];
  const short* w0 = wsc + (size_t)l15 * 256 + quad * 8;
  const short* w1 = wsc + (size_t)(16 + l15) * 256 + quad * 8;
#pragma unroll
  for (int kk = 0; kk < 8; ++kk) {
    bf16x8 a = *(const bf16x8*)(arow + kk * 32);
    acc[0] = __builtin_amdgcn_mfma_f32_16x16x32_bf16(a, *(const bf16x8*)(w0 + kk * 32), acc[0], 0, 0, 0);
    acc[1] = __builtin_amdgcn_mfma_f32_16x16x32_bf16(a, *(const bf16x8*)(w1 + kk * 32), acc[1], 0, 0, 0);
  }
#pragma unroll
  for (int nt = 0; nt < 2; ++nt)
#pragma unroll
    for (int r = 0; r < 4; ++r) {
      const int e = wq * 16 + quad * 4 + r;
      const float v = acc[nt][r];
      const int f = flat[e];
      if (f >= 0 && v > 0.f)
        atomicAdd(&scat_pm[(size_t)f * 32 + nt * 16 + l15], v);
    }
}

// ================ project: concat + 1x1 conv + relu via MFMA -> pm bf16 ================
// block = (b, 128-pixel tile), grid 2048. A = [128 pix][K=64] (50 real + zero pad).
__global__ __launch_bounds__(256) void k_projmfma(const float* __restrict__ scat_pm,
                                                  const float* __restrict__ xin,
                                                  const short* __restrict__ wproj,
                                                  const float* __restrict__ pb,
                                                  short* __restrict__ h0pm) {
  constexpr int PK = 72;  // shorts; 36 words = 4 mod 32 -> 2-way (free); 16B aligned
  __shared__ short abf[128 * PK];
  const int tid = threadIdx.x;
  const int b = blockIdx.x >> 5;
  const int yx0 = (blockIdx.x & 31) << 7;
  // scat (pm, contiguous float4s): ci 0..31
  const float4* sg = (const float4*)(scat_pm + ((size_t)(b * 4096 + yx0)) * 32);
  for (int i = tid; i < 1024; i += 256) {
    const int p = i >> 3, c4 = i & 7;
    const float4 v = sg[(size_t)p * 8 + c4];
    bf16x4 o;
    o[0] = f2bs(v.x); o[1] = f2bs(v.y); o[2] = f2bs(v.z); o[3] = f2bs(v.w);
    *(bf16x4*)(&abf[p * PK + c4 * 4]) = o;
  }
  // xin (ch-major runs): ci 32..49
  for (int i = tid; i < 2304; i += 256) {
    const int run = i >> 7, p = i & 127;
    abf[p * PK + 32 + run] = f2bs(xin[(size_t)(b * 18 + run) * 4096 + yx0 + p]);
  }
  // zero k = 50..65 (MFMA reads k<64)
  for (int i = tid; i < 2048; i += 256) {
    const int p = i >> 4, k = 50 + (i & 15);
    abf[p * PK + k] = 0;
  }
  __syncthreads();
  const int wq = __builtin_amdgcn_readfirstlane(tid >> 6);
  const int lane = tid & 63;
  const int l15 = lane & 15, quad = lane >> 4;
  f32x4 acc[2][2];
#pragma unroll
  for (int t = 0; t < 2; ++t)
#pragma unroll
    for (int n = 0; n < 2; ++n) acc[t][n] = (f32x4){0.f, 0.f, 0.f, 0.f};
  const short* wb0 = wproj + (size_t)l15 * 64 + quad * 8;
  const short* wb1 = wproj + (size_t)(16 + l15) * 64 + quad * 8;
#pragma unroll
  for (int kk = 0; kk < 2; ++kk) {
    const bf16x8 b0 = *(const bf16x8*)(wb0 + kk * 32);
    const bf16x8 b1 = *(const bf16x8*)(wb1 + kk * 32);
#pragma unroll
    for (int t = 0; t < 2; ++t) {
      const int pix = (wq * 2 + t) * 16 + l15;
      bf16x8 a = *(const bf16x8*)(&abf[pix * PK + quad * 8 + kk * 32]);
      acc[t][0] = __builtin_amdgcn_mfma_f32_16x16x32_bf16(a, b0, acc[t][0], 0, 0, 0);
      acc[t][1] = __builtin_amdgcn_mfma_f32_16x16x32_bf16(a, b1, acc[t][1], 0, 0, 0);
    }
  }
#pragma unroll
  for (int t = 0; t < 2; ++t)
#pragma unroll
    for (int n = 0; n < 2; ++n) {
      const int co = n * 16 + l15;
      const float bv = pb[co];
#pragma unroll
      for (int r = 0; r < 4; ++r) {
        const int pix = (wq * 2 + t) * 16 + quad * 4 + r;
        float v = acc[t][n][r] + bv;
        v = v > 0.f ? v : 0.f;
        h0pm[((size_t)(b * 4096 + yx0 + pix)) * 32 + co] = f2bs(v);
      }
    }
}

// ---------------- 4x4 s2 p1 conv + bias + relu via MFMA, pm bf16 in/out ----------------
template <int CIN, int COUT, int HIN, int ROWSO, int COSPLIT, int MT, int NT, int OUTMODE>
__global__ __launch_bounds__(256) void k_ds2(const short* __restrict__ inpm,
                                             const short* __restrict__ wT,
                                             const float* __restrict__ bias,
                                             short* __restrict__ outbf,
                                             float* __restrict__ outf,
                                             float* __restrict__ msf) {
  constexpr int HOUT = HIN / 2;
  constexpr int ROWS = 2 * ROWSO + 2;
  constexpr int COLS = HIN + 2;
  constexpr int CHUNKS = CIN / 8;
  constexpr int KK = CIN / 32;
  constexpr int CIPAD = CIN + 8;
  constexpr int NHO = HOUT / ROWSO;
  __shared__ short lin[ROWS * COLS * CIPAD];
  const int tid = threadIdx.x;
  int bx = blockIdx.x;
  const int co_blk = (COSPLIT > 1) ? (bx % COSPLIT) : 0;
  if (COSPLIT > 1) bx /= COSPLIT;
  const int hoblk = bx % NHO;
  const int b = bx / NHO;
  for (int i = tid; i < ROWS * COLS * CHUNKS; i += 256) {
    const int ch = i % CHUNKS;
    const int pixv = i / CHUNKS;
    const int r = pixv / COLS, c = pixv % COLS;
    const int hi = 2 * ROWSO * hoblk - 1 + r;
    const int wc = c - 1;
    bf16x8 v = (bf16x8)(short)0;
    if (hi >= 0 && hi < HIN && wc >= 0 && wc < HIN)
      v = *(const bf16x8*)(inpm + ((size_t)(b * HIN + hi) * HIN + wc) * CIN + ch * 8);
    *(bf16x8*)(&lin[(r * COLS + c) * CIPAD + ch * 8]) = v;
  }
  __syncthreads();
  const int wq = __builtin_amdgcn_readfirstlane(tid >> 6);
  const int lane = tid & 63;
  const int l15 = lane & 15, quad = lane >> 4;
  const int mtile = (MT > 1) ? (wq % MT) : 0;
  const int cogrp = wq / MT;
  const int cobase = co_blk * (COUT / COSPLIT) + cogrp * (NT * 16);
  const int p = mtile * 16 + l15;
  const int dr = p / HOUT;
  const int col = p % HOUT;
  f32x4 acc[NT];
#pragma unroll
  for (int n = 0; n < NT; ++n) acc[n] = (f32x4){0.f, 0.f, 0.f, 0.f};
  const short* wrow = wT + (size_t)(cobase + l15) * CIN + quad * 8;
  for (int ky = 0; ky < 4; ++ky) {
    for (int kx = 0; kx < 4; ++kx) {
      const short* arow = &lin[((2 * dr + ky) * COLS + 2 * col + kx) * CIPAD + quad * 8];
      const short* wt = wrow + (size_t)(ky * 4 + kx) * COUT * CIN;
#pragma unroll
      for (int kk = 0; kk < KK; ++kk) {
        bf16x8 a = *(const bf16x8*)(arow + kk * 32);
#pragma unroll
        for (int n = 0; n < NT; ++n) {
          bf16x8 bf = *(const bf16x8*)(wt + n * 16 * CIN + kk * 32);
          acc[n] = __builtin_amdgcn_mfma_f32_16x16x32_bf16(a, bf, acc[n], 0, 0, 0);
        }
      }
    }
  }
#pragma unroll
  for (int n = 0; n < NT; ++n) {
    const int co = cobase + n * 16 + l15;
    const float bv = bias[co];
#pragma unroll
    for (int r = 0; r < 4; ++r) {
      const int pp = mtile * 16 + quad * 4 + r;
      const int dr2 = pp / HOUT;
      const int c2 = pp % HOUT;
      const int ho = hoblk * ROWSO + dr2;
      float v = acc[n][r] + bv;
      v = v > 0.f ? v : 0.f;
      const size_t o = ((size_t)b * HOUT * HOUT + ho * HOUT + c2) * COUT + co;
      outbf[o] = f2bs(v);
      if (OUTMODE == 1) {
        outf[o] = v;
        msf[o] = v;
      }
    }
  }
}

// ---------------- 3x3 s1 p1 conv on 8x8 via MFMA, fused stats ----------------
template <int BNIN>
__global__ __launch_bounds__(256) void k_resmfma(const short* __restrict__ hbfin,
                                                 const float* __restrict__ fin,
                                                 const float* __restrict__ statsIn,
                                                 const float* __restrict__ gIn,
                                                 const float* __restrict__ bIn,
                                                 const short* __restrict__ wT,
                                                 float* __restrict__ outpm,
                                                 float* __restrict__ statsOut) {
  constexpr int CIPAD = 136;
  __shared__ short lin[100 * CIPAD];
  __shared__ float bnsc[128], bnsh[128];
  const int tid = threadIdx.x;
  const int b = blockIdx.x >> 3;
  const int cobase = (blockIdx.x & 7) << 4;
  if (BNIN == 1) {
    if (tid < 128) {
      const float mu = statsIn[tid] * (1.f / 4096.f);
      const float var = statsIn[128 + tid] * (1.f / 4096.f) - mu * mu;
      const float sc = gIn[tid] * rsqrtf(var + 1e-5f);
      bnsc[tid] = sc;
      bnsh[tid] = bIn[tid] - mu * sc;
    }
    __syncthreads();
  }
  if (BNIN == 0) {
    const short* hb = hbfin + ((size_t)b << 13);
    for (int i = tid; i < 1600; i += 256) {
      const int pixel = i >> 4, ch = i & 15;
      const int r = pixel / 10, c = pixel % 10;
      bf16x8 v = (bf16x8)(short)0;
      if (r >= 1 && r <= 8 && c >= 1 && c <= 8)
        v = *(const bf16x8*)(hb + (((r - 1) << 3) + (c - 1)) * 128 + ch * 8);
      *(bf16x8*)(&lin[pixel * CIPAD + ch * 8]) = v;
    }
  } else {
    const float* fb = fin + ((size_t)b << 13);
    for (int i = tid; i < 3200; i += 256) {
      const int pixel = i >> 5, c4 = i & 31;
      const int r = pixel / 10, c = pixel % 10;
      bf16x4 o = (bf16x4)(short)0;
      if (r >= 1 && r <= 8 && c >= 1 && c <= 8) {
        const float4 x = *(const float4*)(fb + (size_t)(((r - 1) << 3) + (c - 1)) * 128 + c4 * 4);
        const float xv[4] = {x.x, x.y, x.z, x.w};
#pragma unroll
        for (int k = 0; k < 4; ++k) {
          const int ci = c4 * 4 + k;
          const float v = xv[k] * bnsc[ci] + bnsh[ci];
          o[k] = f2bs(v > 0.f ? v : 0.f);
        }
      }
      *(bf16x4*)(&lin[pixel * CIPAD + c4 * 4]) = o;
    }
  }
  __syncthreads();
  const int wq = __builtin_amdgcn_readfirstlane(tid >> 6);
  const int lane = tid & 63;
  const int l15 = lane & 15, quad = lane >> 4;
  const int p = wq * 16 + l15;
  const int py = p >> 3, px = p & 7;
  f32x4 acc = (f32x4){0.f, 0.f, 0.f, 0.f};
  const short* wrow = wT + (size_t)(cobase + l15) * 128 + quad * 8;
  for (int t = 0; t < 9; ++t) {
    const int ky = t / 3, kx = t % 3;
    const short* arow = &lin[((py + ky) * 10 + px + kx) * CIPAD + quad * 8];
    const short* wt = wrow + (size_t)t * 16384;
#pragma unroll
    for (int kk = 0; kk < 4; ++kk) {
      bf16x8 a = *(const bf16x8*)(arow + kk * 32);
      bf16x8 bf = *(const bf16x8*)(wt + kk * 32);
      acc = __builtin_amdgcn_mfma_f32_16x16x32_bf16(a, bf, acc, 0, 0, 0);
    }
  }
  float* ob = outpm + ((size_t)b << 13);
  const int co = cobase + l15;
  float s = 0.f, q = 0.f;
#pragma unroll
  for (int r = 0; r < 4; ++r) {
    const float v = acc[r];
    ob[(size_t)(wq * 16 + quad * 4 + r) * 128 + co] = v;
    s += v;
    q += v * v;
  }
  s += __shfl_down(s, 32); q += __shfl_down(q, 32);
  s += __shfl_down(s, 16); q += __shfl_down(q, 16);
  if (lane < 16) {
    atomicAdd(&statsOut[co], s);
    atomicAdd(&statsOut[128 + co], q);
  }
}

// ---------------- BN + residual + relu + map_skip accumulate (pixel-major) ----------------
__global__ __launch_bounds__(256) void k_bnadd(const float* __restrict__ inpm,
                                               const float* __restrict__ stats,
                                               const float* __restrict__ g,
                                               const float* __restrict__ bb,
                                               const float* __restrict__ identpm,
                                               float* __restrict__ houtpm,
                                               short* __restrict__ houtbf,
                                               float* __restrict__ mspm) {
  const int idx = blockIdx.x * 256 + threadIdx.x;
  const int co = idx & 127;
  const float mu = stats[co] * (1.f / 4096.f);
  const float var = stats[128 + co] * (1.f / 4096.f) - mu * mu;
  float v = g[co] * (inpm[idx] - mu) * rsqrtf(var + 1e-5f) + bb[co];
  v += identpm[idx];
  v = v > 0.f ? v : 0.f;
  houtpm[idx] = v;
  houtbf[idx] = f2bs(v);
  mspm[idx] += v;
}

// ---------------- map_skip transpose: pm [b][pix][co] -> canonical [b][co][pix] ----------------
__global__ __launch_bounds__(256) void k_mstrans(const float* __restrict__ mspm,
                                                 float* __restrict__ out0) {
  __shared__ float t[64 * 132];
  const int b = blockIdx.x;
  const int tid = threadIdx.x;
  const float* sp = mspm + ((size_t)b << 13);
  for (int i = tid; i < 8192; i += 256) {
    const int pix = i >> 7, co = i & 127;
    t[pix * 132 + co] = sp[i];
  }
  __syncthreads();
  float* dp = out0 + ((size_t)b << 13);
  for (int i = tid; i < 8192; i += 256) {
    const int co = i >> 6, pix = i & 63;
    dp[i] = t[pix * 132 + co];
  }
}

// ---------------- FC via MFMA: k-split partials ----------------
__global__ __launch_bounds__(256) void k_fcmfma(const short* __restrict__ hbf,
                                                const short* __restrict__ wbf,
                                                float* __restrict__ part) {
  const int nb = blockIdx.x & 3;
  const int kb = blockIdx.x >> 2;
  const int wq = __builtin_amdgcn_readfirstlane((int)(threadIdx.x >> 6));
  const int lane = threadIdx.x & 63;
  const int l15 = lane & 15, quad = lane >> 4;
  const int k0 = kb * 256 + quad * 8;
  const short* wp = wbf + (size_t)(nb * 64 + wq * 16 + l15) * 8192 + k0;
  const short* hp = hbf + (size_t)l15 * 8192 + k0;
  f32x4 acc[4];
#pragma unroll
  for (int m = 0; m < 4; ++m) acc[m] = (f32x4){0.f, 0.f, 0.f, 0.f};
  for (int ks = 0; ks < 8; ++ks) {
    bf16x8 bfr = *(const bf16x8*)(wp + ks * 32);
#pragma unroll
    for (int m = 0; m < 4; ++m) {
      bf16x8 a = *(const bf16x8*)(hp + (size_t)m * 16 * 8192 + ks * 32);
      acc[m] = __builtin_amdgcn_mfma_f32_16x16x32_bf16(a, bfr, acc[m], 0, 0, 0);
    }
  }
#pragma unroll
  for (int m = 0; m < 4; ++m)
#pragma unroll
    for (int r = 0; r < 4; ++r) {
      const int b = m * 16 + quad * 4 + r;
      part[((size_t)kb * 64 + b) * 256 + nb * 64 + wq * 16 + l15] = acc[m][r];
    }
}

__global__ __launch_bounds__(256) void k_fcred(const float* __restrict__ part,
                                               const float* __restrict__ bias,
                                               float* __restrict__ out1) {
  const int idx = blockIdx.x * 256 + threadIdx.x;
  const int j = idx & 255;
  float s = 0.f;
#pragma unroll 8
  for (int kb = 0; kb < 32; ++kb) s += part[(size_t)kb * 16384 + idx];
  const float v = s + bias[j];
  out1[idx] = v > 0.f ? v : 0.f;
}

extern "C" void kernel_launch(void* const* d_in, const int* in_sizes, int n_in,
                              void* d_out, int out_size, void* d_ws, size_t ws_size,
                              hipStream_t stream) {
  const float* xin = (const float*)d_in[0];
  const float* emb = (const float*)d_in[1];
  const int* xy = (const int*)d_in[2];
  const float* c1w = (const float*)d_in[3];
  const float* pw = (const float*)d_in[4];
  const float* pb = (const float*)d_in[5];
  const float* d1w = (const float*)d_in[6];
  const float* d1b = (const float*)d_in[7];
  const float* d2w = (const float*)d_in[8];
  const float* d2b = (const float*)d_in[9];
  const float* d3w = (const float*)d_in[10];
  const float* d3b = (const float*)d_in[11];
  const float* rc1w = (const float*)d_in[12];
  const float* rbn1g = (const float*)d_in[13];
  const float* rbn1b = (const float*)d_in[14];
  const float* rc2w = (const float*)d_in[15];
  const float* rbn2g = (const float*)d_in[16];
  const float* rbn2b = (const float*)d_in[17];
  const float* fcw = (const float*)d_in[18];
  const float* fcb = (const float*)d_in[19];

  float* out0 = (float*)d_out;   // map_skip [64,128,8,8] f32
  float* out1 = out0 + 524288;   // embedded_spatial [64,256] f32

  float* F = (float*)d_ws;
  float* scat = F + 0;           // scat_pm [64][4096][32] f32 — dead after projmfma; reused:
  float* h1pm_f = F + 0;
  float* h2pm_f = F + 2097152;
  float* hApm = F + 3145728;
  float* hBpm = F + 3670016;
  float* tmppm = F + 4194304;
  float* tmp2pm = F + 4718592;
  float* mspm = F + 5242880;
  short* pmbfA = (short*)(F + 5767168);
  short* pmbfB = (short*)(F + 6029312);
  float* stats = F + 6291456;
  float* fcpart = F + 6293504;   // ends 6817792 < 8388608
  short* h0pm = (short*)(F + 8388608);    // [64][4096][32] bf16
  short* wfcbf = (short*)(F + 12582912);
  short* wTr1 = (short*)(F + 13631488);
  short* wTr2 = wTr1 + 589824;
  short* wTds1 = wTr2 + 589824;
  short* wTds2 = wTds1 + 32768;
  short* wTds3 = wTds2 + 131072;
  short* wsc = wTds3 + 262144;            // 8192 shorts
  short* wproj = wsc + 8192;              // 2048 shorts; ends ~57.8 MB

  hipMemsetAsync(scat, 0, 8388608 * sizeof(float), stream);
  k_wall<<<6568, 256, 0, stream>>>(rc1w, rc2w, d1w, d2w, d3w, fcw, c1w, pw,
                                   wTr1, wTr2, wTds1, wTds2, wTds3, wfcbf, wsc, wproj);
  k_scatmfma<<<512, 256, 0, stream>>>(emb, xy, wsc, scat);
  k_projmfma<<<2048, 256, 0, stream>>>(scat, xin, wproj, pb, h0pm);
  hipMemsetAsync(stats, 0, 2048 * sizeof(float), stream);  // scat region dead from here
  short* h1pm = (short*)h1pm_f;
  short* h2pm = (short*)h2pm_f;
  k_ds2<32, 64, 64, 2, 1, 4, 4, 0><<<1024, 256, 0, stream>>>(h0pm, wTds1, d1b, h1pm, hApm, mspm);
  k_ds2<64, 128, 32, 1, 1, 1, 2, 0><<<1024, 256, 0, stream>>>(h1pm, wTds2, d2b, h2pm, hApm, mspm);
  k_ds2<128, 128, 16, 2, 2, 1, 1, 1><<<512, 256, 0, stream>>>(h2pm, wTds3, d3b, pmbfA, hApm, mspm);

  float* cur = hApm;  float* nxt = hBpm;
  short* curbf = pmbfA; short* nxtbf = pmbfB;
  for (int i = 0; i < 4; ++i) {
    float* sA = stats + i * 512;
    float* sB = stats + i * 512 + 256;
    k_resmfma<0><<<512, 256, 0, stream>>>(curbf, nullptr, nullptr, nullptr, nullptr,
                                          wTr1 + (size_t)i * 147456, tmppm, sA);
    k_resmfma<1><<<512, 256, 0, stream>>>(nullptr, tmppm, sA, rbn1g + i * 128, rbn1b + i * 128,
                                          wTr2 + (size_t)i * 147456, tmp2pm, sB);
    k_bnadd<<<2048, 256, 0, stream>>>(tmp2pm, sB, rbn2g + i * 128, rbn2b + i * 128, cur, nxt,
                                      nxtbf, mspm);
    float* sw = cur; cur = nxt; nxt = sw;
    short* swb = curbf; curbf = nxtbf; nxtbf = swb;
  }
  k_mstrans<<<64, 256, 0, stream>>>(mspm, out0);
  k_fcmfma<<<128, 256, 0, stream>>>(curbf, wfcbf, fcpart);
  k_fcred<<<64, 256, 0, stream>>>(fcpart, fcb, out1);
}